// Round 5
// baseline (3893.251 us; speedup 1.0000x reference)
//
#include <hip/hip_runtime.h>
#include <math.h>

#define NN     100000
#define NE     1600000
#define FEAT   128
#define GQ     4
#define NL     3
#define NGR    64
#define NCLS   10
#define KSPL   512
#define NKS    10            /* K-steps of 64 (640 total) */
#define BM     64
#define NB     1563          /* dst buckets of 64 nodes: ceil(NN/64) */
#define NCHUNK 256
#define CHUNK  6250          /* NE / NCHUNK */

typedef __attribute__((ext_vector_type(8))) short short8;
typedef __attribute__((ext_vector_type(4))) float floatx4;

__device__ __forceinline__ float fsilu(float x){ return x / (1.f + __expf(-x)); }
__device__ __forceinline__ ushort f2bf(float f){
  uint u = __builtin_bit_cast(uint, f);
  return (ushort)((u + 0x7FFFu + ((u >> 16) & 1u)) >> 16);
}
__device__ __forceinline__ float bf2f(ushort h){ return __builtin_bit_cast(float, ((uint)h) << 16); }

// ---------------- small utility kernels ----------------
__global__ __launch_bounds__(256) void k_zero_i(int* __restrict__ p, int n){
  int i = blockIdx.x*256 + threadIdx.x; if (i < n) p[i] = 0;
}
__global__ __launch_bounds__(256) void k_zero_f(float* __restrict__ p, int n){
  int i = blockIdx.x*256 + threadIdx.x; if (i < n) p[i] = 0.f;
}
__global__ __launch_bounds__(256) void k_hist(const int* __restrict__ dst, int* __restrict__ hist, int ne){
  int e = blockIdx.x*256 + threadIdx.x; if (e < ne) atomicAdd(&hist[dst[e]], 1);
}
__global__ __launch_bounds__(256) void k_dinv(const int* __restrict__ hist, float* __restrict__ dinv, int n){
  int i = blockIdx.x*256 + threadIdx.x; if (i < n) dinv[i] = rsqrtf((float)hist[i] + 1.f);
}

// ---- chunk-private binning: each block bins its 6250 edges by dst>>6 into its own region ----
// edge packed as (src<<6) | (dst&63)  -- src < 2^17, fits 23 bits
__global__ __launch_bounds__(256) void k_binA(const int* __restrict__ src, const int* __restrict__ dst,
                                              uint* __restrict__ priv, int* __restrict__ seg){
  __shared__ int hist[NB];
  __shared__ int cur[NB];
  __shared__ int scanbuf[256];
  const int c = blockIdx.x, tid = threadIdx.x;
  const size_t e0 = (size_t)c * CHUNK;
  for (int i = tid; i < NB; i += 256) hist[i] = 0;
  __syncthreads();
  for (int i = tid; i < CHUNK; i += 256) atomicAdd(&hist[dst[e0+i] >> 6], 1);
  __syncthreads();
  // in-block exclusive scan over NB entries (7 per thread)
  int loc[7]; int s = 0;
  const int base = tid * 7;
  #pragma unroll
  for (int j = 0; j < 7; ++j){ int idx = base+j; int v = (idx < NB) ? hist[idx] : 0; loc[j] = s; s += v; }
  scanbuf[tid] = s;
  __syncthreads();
  for (int off = 1; off < 256; off <<= 1){
    int u = (tid >= off) ? scanbuf[tid-off] : 0;
    __syncthreads();
    scanbuf[tid] += u;
    __syncthreads();
  }
  const int run = scanbuf[tid] - s;
  #pragma unroll
  for (int j = 0; j < 7; ++j){
    int idx = base+j;
    if (idx < NB){ int st = run + loc[j]; seg[c*(NB+1)+idx] = st; cur[idx] = st; }
  }
  if (tid == 0) seg[c*(NB+1)+NB] = CHUNK;
  __syncthreads();
  for (int i = tid; i < CHUNK; i += 256){
    const uint ss = (uint)src[e0+i], dd = (uint)dst[e0+i];
    const int p = atomicAdd(&cur[dd >> 6], 1);
    priv[(size_t)c*CHUNK + p] = (ss << 6) | (dd & 63u);
  }
}

// per-bucket edge totals from node histogram (hist padded to NB*64 entries)
__global__ __launch_bounds__(256) void k_btot(const int* __restrict__ hist, int* __restrict__ btot){
  const int b = blockIdx.x*256 + threadIdx.x;
  if (b >= NB) return;
  const int4* h4 = (const int4*)(hist + (size_t)b*64);
  int s = 0;
  #pragma unroll
  for (int i = 0; i < 16; ++i){ int4 v = h4[i]; s += v.x + v.y + v.z + v.w; }
  btot[b] = s;
}

// single-block exclusive scan over NB bucket totals
__global__ __launch_bounds__(256) void k_bscan(const int* __restrict__ btot, int* __restrict__ bstart){
  __shared__ int scanbuf[256];
  const int tid = threadIdx.x;
  int loc[7]; int s = 0;
  const int base = tid * 7;
  #pragma unroll
  for (int j = 0; j < 7; ++j){ int idx = base+j; int v = (idx < NB) ? btot[idx] : 0; loc[j] = s; s += v; }
  scanbuf[tid] = s;
  __syncthreads();
  for (int off = 1; off < 256; off <<= 1){
    int u = (tid >= off) ? scanbuf[tid-off] : 0;
    __syncthreads();
    scanbuf[tid] += u;
    __syncthreads();
  }
  const int run = scanbuf[tid] - s;
  #pragma unroll
  for (int j = 0; j < 7; ++j){
    int idx = base+j;
    if (idx < NB) bstart[idx] = run + loc[j];
  }
  if (tid == 0) bstart[NB] = NE;
}

// transpose: bucket b's edges from all 256 chunk-private regions -> contiguous ebuf
__global__ __launch_bounds__(256) void k_gathE(const uint* __restrict__ priv, const int* __restrict__ seg,
                                               const int* __restrict__ bstart, uint* __restrict__ ebuf){
  __shared__ int sc[256];
  const int b = blockIdx.x, c = threadIdx.x;
  const int s0 = seg[c*(NB+1) + b], s1 = seg[c*(NB+1) + b + 1];
  const int cnt = s1 - s0;
  sc[c] = cnt;
  __syncthreads();
  for (int off = 1; off < 256; off <<= 1){
    int u = (c >= off) ? sc[c-off] : 0;
    __syncthreads();
    sc[c] += u;
    __syncthreads();
  }
  int dsti = bstart[b] + sc[c] - cnt;
  const size_t pbase = (size_t)c*CHUNK + s0;
  for (int i = 0; i < cnt; ++i) ebuf[dsti + i] = priv[pbase + i];
}

// weights -> bf16, concat [sW|bW] as W[n][k], pre-swizzled per 64-k tile image
__global__ __launch_bounds__(256) void k_wprep(const float* __restrict__ sW, const float* __restrict__ bW,
                                               ushort* __restrict__ wimg){
  int idx = blockIdx.x*256 + threadIdx.x;       // ((l*10+q)*128+n)*64+kk
  if (idx >= NL*NKS*128*64) return;
  int kk = idx & 63;
  int n  = (idx >> 6) & 127;
  int q  = (idx >> 13) % NKS;
  int l  = idx / (NKS*128*64);
  int kg = q*64 + kk;
  float v = (kg < KSPL) ? sW[((size_t)l*FEAT + n)*KSPL + kg]
                        : bW[((size_t)l*FEAT + n)*FEAT + (kg - KSPL)];
  size_t tile = ((size_t)l*NKS + q) * (128*64);
  uint byte_in_row = ((uint)(kk*2)) ^ (((uint)(n & 7)) << 4);
  wimg[tile + (size_t)n*64 + (byte_in_row >> 1)] = f2bf(v);
}

// ---------------- FKAN transform: fused LN + RBF + MFMA GEMM ----------------
template <typename TIn>
__global__ __launch_bounds__(256) void k_fkan(
    const TIn* __restrict__ xin,            // [NN][128] fp32 or bf16(ushort)
    const ushort* __restrict__ wimg,        // this layer's pre-swizzled image (10*8192 ushorts)
    const float* __restrict__ ln_s, const float* __restrict__ ln_b,
    const float* __restrict__ sb, const float* __restrict__ bb,
    const float* __restrict__ dinv,
    ushort* __restrict__ hprime)
{
  __shared__ char zb[64*256];        // z bf16 [64][128], xor-swizzled rows
  __shared__ char sA[2*8192];        // silu(x) A-tiles for q=8,9  [64][64] bf16 swizzled
  __shared__ char At[8192];          // basis A-tile [64][64] bf16 swizzled
  __shared__ char Bt[16384];         // B tile [128 n][64 k] bf16 swizzled
  __shared__ float lnS[128], lnB[128], sbias[128];

  const int tid  = threadIdx.x;
  const int lane = tid & 63, wv = tid >> 6;
  const int node0 = blockIdx.x * BM;

  if (tid < 128){ lnS[tid] = ln_s[tid]; lnB[tid] = ln_b[tid]; sbias[tid] = sb[tid] + bb[tid]; }

  // ---- layernorm phase: 4 threads per node ----
  const int lm = tid >> 2, part = tid & 3;
  const int node = node0 + lm;
  float xv[32];
  if (node < NN){
    if constexpr (sizeof(TIn) == 4){
      const float4* xr = (const float4*)((const float*)xin + (size_t)node*FEAT + part*32);
      #pragma unroll
      for (int j = 0; j < 8; ++j){ float4 v = xr[j]; xv[4*j]=v.x; xv[4*j+1]=v.y; xv[4*j+2]=v.z; xv[4*j+3]=v.w; }
    } else {
      const uint4* xr = (const uint4*)((const ushort*)xin + (size_t)node*FEAT + part*32);
      #pragma unroll
      for (int j = 0; j < 4; ++j){
        uint4 v = xr[j];
        uint w0=v.x, w1=v.y, w2=v.z, w3=v.w;
        xv[8*j+0]=bf2f((ushort)(w0&0xffff)); xv[8*j+1]=bf2f((ushort)(w0>>16));
        xv[8*j+2]=bf2f((ushort)(w1&0xffff)); xv[8*j+3]=bf2f((ushort)(w1>>16));
        xv[8*j+4]=bf2f((ushort)(w2&0xffff)); xv[8*j+5]=bf2f((ushort)(w2>>16));
        xv[8*j+6]=bf2f((ushort)(w3&0xffff)); xv[8*j+7]=bf2f((ushort)(w3>>16));
      }
    }
  } else {
    #pragma unroll
    for (int j = 0; j < 32; ++j) xv[j] = 0.f;
  }
  float s1 = 0.f, s2 = 0.f;
  #pragma unroll
  for (int j = 0; j < 32; ++j){ s1 += xv[j]; s2 += xv[j]*xv[j]; }
  s1 += __shfl_xor(s1, 1); s2 += __shfl_xor(s2, 1);
  s1 += __shfl_xor(s1, 2); s2 += __shfl_xor(s2, 2);
  const float mean = s1 * (1.f/128.f);
  const float var  = s2 * (1.f/128.f) - mean*mean;
  const float rs   = rsqrtf(var + 1e-5f);
  __syncthreads();                       // lnS/lnB staged
  {
    const uint swl = ((uint)(lm & 7)) << 4;
    #pragma unroll
    for (int j = 0; j < 32; j += 2){
      const int f = part*32 + j;
      float z0 = (xv[j]   - mean)*rs*lnS[f]   + lnB[f];
      float z1 = (xv[j+1] - mean)*rs*lnS[f+1] + lnB[f+1];
      *(uint*)(zb + lm*256 + (((uint)(f*2)) ^ swl)) = (uint)f2bf(z0) | ((uint)f2bf(z1) << 16);
      float u0 = fsilu(xv[j]), u1 = fsilu(xv[j+1]);
      const int qp = f >> 6, kk = f & 63;
      *(uint*)(sA + qp*8192 + lm*128 + (((uint)(kk*2)) ^ swl)) = (uint)f2bf(u0) | ((uint)f2bf(u1) << 16);
    }
  }
  __syncthreads();                       // zb, sA ready

  // ---- MFMA K-loop ----
  const int l15 = lane & 15, l4h = lane >> 4;
  const int wm = wv >> 1, wn = wv & 1;
  floatx4 acc[2][4];
  #pragma unroll
  for (int mr = 0; mr < 2; ++mr)
    #pragma unroll
    for (int nr = 0; nr < 4; ++nr){ floatx4 z4 = {0.f,0.f,0.f,0.f}; acc[mr][nr] = z4; }

  int rowA[2]; uint swA[2];
  #pragma unroll
  for (int mr = 0; mr < 2; ++mr){ rowA[mr] = wm*32 + mr*16 + l15; swA[mr] = ((uint)(rowA[mr] & 7)) << 4; }
  int colB[4]; uint swB[4];
  #pragma unroll
  for (int nr = 0; nr < 4; ++nr){ colB[nr] = wn*64 + nr*16 + l15; swB[nr] = ((uint)(colB[nr] & 7)) << 4; }

  for (int q = 0; q < NKS; ++q){
    // stage B tile (linear copy of pre-swizzled image)
    {
      const short8* gs = (const short8*)(wimg + (size_t)q*8192);
      short8* lsd = (short8*)Bt;
      lsd[tid      ] = gs[tid      ];
      lsd[tid + 256] = gs[tid + 256];
      lsd[tid + 512] = gs[tid + 512];
      lsd[tid + 768] = gs[tid + 768];
    }
    const char* Ab;
    if (q < 8){
      // generate basis A-tile: thread -> row (tid&63), 16 k's starting at (tid>>6)*16
      const int am = tid & 63, aw = tid >> 6;
      const uint sws = ((uint)(am & 7)) << 4;
      const int f0 = q*16 + aw*4;
      uint2 zz = *(const uint2*)(zb + am*256 + (((uint)(f0*2)) ^ sws));
      float zf[4];
      zf[0] = bf2f((ushort)(zz.x & 0xffff)); zf[1] = bf2f((ushort)(zz.x >> 16));
      zf[2] = bf2f((ushort)(zz.y & 0xffff)); zf[3] = bf2f((ushort)(zz.y >> 16));
      ushort e[16];
      #pragma unroll
      for (int fi = 0; fi < 4; ++fi)
        #pragma unroll
        for (int g = 0; g < 4; ++g){
          float t = (zf[fi] - (-2.f + (4.f/3.f)*(float)g)) * 0.75f;
          e[fi*4+g] = f2bf(__expf(-t*t));
        }
      short8 p0, p1;
      #pragma unroll
      for (int i = 0; i < 8; ++i){ p0[i] = (short)e[i]; p1[i] = (short)e[8+i]; }
      *(short8*)(At + am*128 + (((uint)(aw*32))      ^ sws)) = p0;
      *(short8*)(At + am*128 + (((uint)(aw*32 + 16)) ^ sws)) = p1;
      Ab = At;
    } else {
      Ab = sA + (q - 8)*8192;
    }
    __syncthreads();
    #pragma unroll
    for (int ks = 0; ks < 2; ++ks){
      const uint kb = (uint)(ks*64 + l4h*16);
      short8 af[2], bfr[4];
      #pragma unroll
      for (int mr = 0; mr < 2; ++mr)
        af[mr] = *(const short8*)(Ab + rowA[mr]*128 + (kb ^ swA[mr]));
      #pragma unroll
      for (int nr = 0; nr < 4; ++nr)
        bfr[nr] = *(const short8*)(Bt + colB[nr]*128 + (kb ^ swB[nr]));
      #pragma unroll
      for (int mr = 0; mr < 2; ++mr)
        #pragma unroll
        for (int nr = 0; nr < 4; ++nr)
          acc[mr][nr] = __builtin_amdgcn_mfma_f32_16x16x32_bf16(af[mr], bfr[nr], acc[mr][nr], 0, 0, 0);
    }
    __syncthreads();
  }

  // ---- epilogue: h' = dinv * (acc + bias), bf16 store ----
  #pragma unroll
  for (int mr = 0; mr < 2; ++mr){
    const int rbase = node0 + wm*32 + mr*16 + l4h*4;
    float dvv[4];
    #pragma unroll
    for (int j = 0; j < 4; ++j) dvv[j] = (rbase + j < NN) ? dinv[rbase + j] : 0.f;
    #pragma unroll
    for (int nr = 0; nr < 4; ++nr){
      const int cf = wn*64 + nr*16 + l15;
      const float sv = sbias[cf];
      #pragma unroll
      for (int j = 0; j < 4; ++j){
        const int r = rbase + j;
        if (r < NN) hprime[(size_t)r*FEAT + cf] = f2bf(dvv[j]*(acc[mr][nr][j] + sv));
      }
    }
  }
}

// ---------------- bucketed aggregation: contiguous edges, LDS fp32 accumulators ----------------
__global__ __launch_bounds__(256) void k_aggC(
    const ushort* __restrict__ hprime, const uint* __restrict__ ebuf,
    const int* __restrict__ bstart, const float* __restrict__ dinv,
    const float* __restrict__ gb, ushort* __restrict__ xout)
{
  __shared__ float accE[64][64];   // even feats: f=2*lane
  __shared__ float accO[64][64];   // odd  feats: f=2*lane+1
  const int b = blockIdx.x, tid = threadIdx.x;
  const int wv = tid >> 6, lane = tid & 63;
  const int n0 = b * 64;
  {
    float4 z4 = {0.f,0.f,0.f,0.f};
    float4* pE = (float4*)accE; float4* pO = (float4*)accO;
    #pragma unroll
    for (int i = 0; i < 4; ++i){ pE[tid + i*256] = z4; pO[tid + i*256] = z4; }
  }
  __syncthreads();
  const uint* h2 = (const uint*)hprime;

  const int e0 = bstart[b], e1 = bstart[b+1];
  const int len = e1 - e0;
  const int per = (len + 3) >> 2;
  int j = e0 + wv*per;
  const int je = min(j + per, e1);
  for (; j + 3 < je; j += 4){
    const uint u0 = ebuf[j], u1 = ebuf[j+1], u2 = ebuf[j+2], u3 = ebuf[j+3];
    const uint w0 = h2[(size_t)(u0 >> 6)*64 + lane];
    const uint w1 = h2[(size_t)(u1 >> 6)*64 + lane];
    const uint w2 = h2[(size_t)(u2 >> 6)*64 + lane];
    const uint w3 = h2[(size_t)(u3 >> 6)*64 + lane];
    atomicAdd(&accE[u0 & 63][lane], bf2f((ushort)(w0 & 0xffff)));
    atomicAdd(&accO[u0 & 63][lane], bf2f((ushort)(w0 >> 16)));
    atomicAdd(&accE[u1 & 63][lane], bf2f((ushort)(w1 & 0xffff)));
    atomicAdd(&accO[u1 & 63][lane], bf2f((ushort)(w1 >> 16)));
    atomicAdd(&accE[u2 & 63][lane], bf2f((ushort)(w2 & 0xffff)));
    atomicAdd(&accO[u2 & 63][lane], bf2f((ushort)(w2 >> 16)));
    atomicAdd(&accE[u3 & 63][lane], bf2f((ushort)(w3 & 0xffff)));
    atomicAdd(&accO[u3 & 63][lane], bf2f((ushort)(w3 >> 16)));
  }
  for (; j < je; ++j){
    const uint u0 = ebuf[j];
    const uint w0 = h2[(size_t)(u0 >> 6)*64 + lane];
    atomicAdd(&accE[u0 & 63][lane], bf2f((ushort)(w0 & 0xffff)));
    atomicAdd(&accO[u0 & 63][lane], bf2f((ushort)(w0 >> 16)));
  }
  __syncthreads();

  // epilogue: x = silu(dinv[d]*(acc + h'[d]) + bias)
  const float2 b2 = *(const float2*)(gb + 2*lane);
  #pragma unroll
  for (int i = 0; i < 16; ++i){
    const int r = wv*16 + i;
    const int d = n0 + r;
    if (d < NN){
      const uint v = h2[(size_t)d*64 + lane];
      float a0 = accE[r][lane] + bf2f((ushort)(v & 0xffff));
      float a1 = accO[r][lane] + bf2f((ushort)(v >> 16));
      const float dv = dinv[d];
      a0 = fsilu(dv*a0 + b2.x);
      a1 = fsilu(dv*a1 + b2.y);
      ((uint*)xout)[(size_t)d*64 + lane] = (uint)f2bf(a0) | ((uint)f2bf(a1) << 16);
    }
  }
}

// ---------------- pooling (sorted batch) ----------------
__global__ __launch_bounds__(128) void k_pool(const ushort* __restrict__ x,
                                              const int* __restrict__ batch,
                                              float* __restrict__ pooled,
                                              float* __restrict__ cnt, int n){
  const int f = threadIdx.x;
  const int start = blockIdx.x * 64;
  const int end   = min(start + 64, n);
  if (start >= end) return;
  int cur = batch[start];
  float acc = 0.f, c = 0.f;
  for (int i = start; i < end; ++i){
    const int b = batch[i];
    if (b != cur){
      atomicAdd(&pooled[(size_t)cur*FEAT + f], acc);
      if (f == 0) atomicAdd(&cnt[cur], c);
      cur = b; acc = 0.f; c = 0.f;
    }
    acc += bf2f(x[(size_t)i*FEAT + f]);
    c += 1.f;
  }
  atomicAdd(&pooled[(size_t)cur*FEAT + f], acc);
  if (f == 0) atomicAdd(&cnt[cur], c);
}

__global__ __launch_bounds__(128) void k_pool_div(float* __restrict__ pooled,
                                                  const float* __restrict__ cnt){
  const int g = blockIdx.x, f = threadIdx.x;
  pooled[(size_t)g*FEAT + f] /= fmaxf(cnt[g], 1.f);
}

// ---------------- readout FastKAN (128 -> 10) + log_softmax ----------------
__global__ __launch_bounds__(128) void k_readout(const float* __restrict__ pooled,
    const float* __restrict__ ln_s, const float* __restrict__ ln_b,
    const float* __restrict__ sW, const float* __restrict__ sb,
    const float* __restrict__ bW, const float* __restrict__ bb,
    float* __restrict__ out){
  __shared__ float cb[KSPL + FEAT];
  __shared__ float wred[2][2];
  __shared__ float outv[NCLS];
  const int tid = threadIdx.x, lane = tid & 63, wave = tid >> 6;
  const int g = blockIdx.x;

  const float xvv = pooled[(size_t)g*FEAT + tid];
  float s1 = xvv, s2 = xvv*xvv;
  #pragma unroll
  for (int off = 32; off; off >>= 1){ s1 += __shfl_down(s1, off); s2 += __shfl_down(s2, off); }
  if (lane == 0){ wred[wave][0] = s1; wred[wave][1] = s2; }
  __syncthreads();
  const float m   = (wred[0][0] + wred[1][0]) * (1.f/FEAT);
  const float var = (wred[0][1] + wred[1][1]) * (1.f/FEAT) - m*m;
  const float rs  = rsqrtf(var + 1e-5f);
  const float z   = (xvv - m) * rs * ln_s[tid] + ln_b[tid];
  #pragma unroll
  for (int gg = 0; gg < GQ; ++gg){
    const float t = (z - (-2.f + (4.f/3.f)*(float)gg)) * 0.75f;
    cb[tid*GQ + gg] = __expf(-t*t);
  }
  cb[KSPL + tid] = fsilu(xvv);
  __syncthreads();

  if (tid < NCLS){
    const float* wr = sW + (size_t)tid*KSPL;
    const float* br = bW + (size_t)tid*FEAT;
    float acc = sb[tid] + bb[tid];
    for (int k = 0; k < KSPL; ++k) acc += cb[k] * wr[k];
    for (int k = 0; k < FEAT; ++k) acc += cb[KSPL + k] * br[k];
    outv[tid] = acc;
  }
  __syncthreads();
  if (tid == 0){
    float mx = -1e30f;
    for (int o = 0; o < NCLS; ++o) mx = fmaxf(mx, outv[o]);
    float se = 0.f;
    for (int o = 0; o < NCLS; ++o) se += __expf(outv[o] - mx);
    const float lse = mx + logf(se);
    for (int o = 0; o < NCLS; ++o) out[(size_t)g*NCLS + o] = outv[o] - lse;
  }
}

extern "C" void kernel_launch(void* const* d_in, const int* in_sizes, int n_in,
                              void* d_out, int out_size, void* d_ws, size_t ws_size,
                              hipStream_t stream) {
  const float* x     = (const float*)d_in[0];
  const int*   edge  = (const int*)d_in[1];
  const int*   batch = (const int*)d_in[2];
  const float* ln_s  = (const float*)d_in[3];
  const float* ln_b  = (const float*)d_in[4];
  const float* sW    = (const float*)d_in[5];
  const float* sb    = (const float*)d_in[6];
  const float* bW    = (const float*)d_in[7];
  const float* bb    = (const float*)d_in[8];
  const float* gcn_b = (const float*)d_in[9];
  const float* ro_ln_s = (const float*)d_in[10];
  const float* ro_ln_b = (const float*)d_in[11];
  const float* ro_sW   = (const float*)d_in[12];
  const float* ro_sb   = (const float*)d_in[13];
  const float* ro_bW   = (const float*)d_in[14];
  const float* ro_bb   = (const float*)d_in[15];
  float* out = (float*)d_out;

  const int* src = edge;
  const int* dst = edge + NE;

  char* W = (char*)d_ws;
  size_t off = 0;
  auto alloc = [&](size_t bytes){ size_t r = off; off += (bytes + 1023) & ~((size_t)1023); return r; };
  float*  dinv   = (float*) (W + alloc((size_t)NN*4));
  ushort* wimg   = (ushort*)(W + alloc((size_t)NL*NKS*8192*2));
  int*    hist   = (int*)   (W + alloc((size_t)NB*64*4));   // padded to NB*64
  uint*   priv   = (uint*)  (W + alloc((size_t)NE*4));
  uint*   ebuf   = (uint*)  (W + alloc((size_t)NE*4));
  int*    seg    = (int*)   (W + alloc((size_t)NCHUNK*(NB+1)*4));
  int*    btot   = (int*)   (W + alloc((size_t)NB*4));
  int*    bstart = (int*)   (W + alloc((size_t)(NB+1)*4));
  ushort* hprime = (ushort*)(W + alloc((size_t)NN*FEAT*2));
  ushort* xcur   = (ushort*)(W + alloc((size_t)NN*FEAT*2));
  float*  pooled = (float*) (W + alloc((size_t)(NGR*FEAT + NGR)*4));
  float*  cnt    = pooled + NGR*FEAT;

  // degree norm + binning + bucket-sorted edge list (layer-invariant)
  k_zero_i<<<(NB*64+255)/256, 256, 0, stream>>>(hist, NB*64);
  k_zero_f<<<(NGR*FEAT+NGR+255)/256, 256, 0, stream>>>(pooled, NGR*FEAT + NGR);
  k_hist<<<(NE+255)/256, 256, 0, stream>>>(dst, hist, NE);
  k_dinv<<<(NN+255)/256, 256, 0, stream>>>(hist, dinv, NN);
  k_binA<<<NCHUNK, 256, 0, stream>>>(src, dst, priv, seg);
  k_btot<<<(NB+255)/256, 256, 0, stream>>>(hist, btot);
  k_bscan<<<1, 256, 0, stream>>>(btot, bstart);
  k_gathE<<<NB, 256, 0, stream>>>(priv, seg, bstart, ebuf);
  k_wprep<<<(NL*NKS*128*64 + 255)/256, 256, 0, stream>>>(sW, bW, wimg);

  const int fkan_grid = (NN + BM - 1) / BM;
  for (int l = 0; l < NL; ++l){
    const ushort* wl = wimg + (size_t)l*NKS*8192;
    if (l == 0)
      k_fkan<float><<<fkan_grid, 256, 0, stream>>>(x, wl,
          ln_s + l*FEAT, ln_b + l*FEAT, sb + l*FEAT, bb + l*FEAT, dinv, hprime);
    else
      k_fkan<ushort><<<fkan_grid, 256, 0, stream>>>(xcur, wl,
          ln_s + l*FEAT, ln_b + l*FEAT, sb + l*FEAT, bb + l*FEAT, dinv, hprime);
    k_aggC<<<NB, 256, 0, stream>>>(hprime, ebuf, bstart, dinv, gcn_b + l*FEAT, xcur);
  }

  k_pool<<<(NN+63)/64, 128, 0, stream>>>(xcur, batch, pooled, cnt, NN);
  k_pool_div<<<NGR, 128, 0, stream>>>(pooled, cnt);
  k_readout<<<NGR, 128, 0, stream>>>(pooled, ro_ln_s, ro_ln_b,
                                     ro_sW, ro_sb, ro_bW, ro_bb, out);
}

// Round 6
// 588.923 us; speedup vs baseline: 6.6108x; 6.6108x over previous
//
#include <hip/hip_runtime.h>
#include <math.h>

#define NN     100000
#define NE     1600000
#define FEAT   128
#define GQ     4
#define NL     3
#define NGR    64
#define NCLS   10
#define KSPL   512
#define NKS    10            /* K-steps of 64 (640 total) */
#define BM     64
#define NB     1563          /* dst buckets of 64 nodes: ceil(NN/64) */
#define NCHUNK 256
#define CHUNK  6250          /* NE / NCHUNK */
#define TILE   1024
#define NT     ((NN + TILE - 1) / TILE)   /* 98 scan tiles */

typedef __attribute__((ext_vector_type(8))) short short8;
typedef __attribute__((ext_vector_type(4))) float floatx4;

__device__ __forceinline__ float fsilu(float x){ return x / (1.f + __expf(-x)); }
__device__ __forceinline__ ushort f2bf(float f){
  uint u = __builtin_bit_cast(uint, f);
  return (ushort)((u + 0x7FFFu + ((u >> 16) & 1u)) >> 16);
}
__device__ __forceinline__ float bf2f(ushort h){ return __builtin_bit_cast(float, ((uint)h) << 16); }

// ---------------- small utility kernels ----------------
__global__ __launch_bounds__(256) void k_zero_i(int* __restrict__ p, int n){
  int i = blockIdx.x*256 + threadIdx.x; if (i < n) p[i] = 0;
}
__global__ __launch_bounds__(256) void k_zero_f(float* __restrict__ p, int n){
  int i = blockIdx.x*256 + threadIdx.x; if (i < n) p[i] = 0.f;
}
__global__ __launch_bounds__(256) void k_hist(const int* __restrict__ dst, int* __restrict__ hist, int ne){
  int e = blockIdx.x*256 + threadIdx.x; if (e < ne) atomicAdd(&hist[dst[e]], 1);
}

// ---- hierarchical exclusive scan over hist[NN] -> rp, dinv ----
__global__ __launch_bounds__(256) void k_scan_a(const int* __restrict__ hist, int* __restrict__ tsum){
  __shared__ int red[4];
  const int base = blockIdx.x * TILE;
  int s = 0;
  #pragma unroll
  for (int j = 0; j < 4; ++j){
    int idx = base + threadIdx.x + j*256;
    if (idx < NN) s += hist[idx];
  }
  #pragma unroll
  for (int off = 32; off; off >>= 1) s += __shfl_down(s, off);
  if ((threadIdx.x & 63) == 0) red[threadIdx.x >> 6] = s;
  __syncthreads();
  if (threadIdx.x == 0) tsum[blockIdx.x] = red[0] + red[1] + red[2] + red[3];
}

__global__ __launch_bounds__(128) void k_scan_b(const int* __restrict__ tsum,
                                                int* __restrict__ toff, int* __restrict__ rpN){
  __shared__ int lds[128];
  const int tid = threadIdx.x;
  int v = (tid < NT) ? tsum[tid] : 0;
  lds[tid] = v; __syncthreads();
  for (int off = 1; off < 128; off <<= 1){
    int u = (tid >= off) ? lds[tid - off] : 0;
    __syncthreads();
    lds[tid] += u;
    __syncthreads();
  }
  if (tid < NT) toff[tid] = lds[tid] - v;
  if (tid == NT - 1) *rpN = lds[tid];
}

__global__ __launch_bounds__(256) void k_scan_c(const int* __restrict__ hist,
                                                const int* __restrict__ toff,
                                                int* __restrict__ rp,
                                                float* __restrict__ dinv){
  __shared__ int lds[256];
  const int tid = threadIdx.x;
  const int base = blockIdx.x * TILE + tid*4;
  int h[4]; int s = 0;
  #pragma unroll
  for (int j = 0; j < 4; ++j){ int idx = base + j; h[j] = (idx < NN) ? hist[idx] : 0; s += h[j]; }
  lds[tid] = s; __syncthreads();
  for (int off = 1; off < 256; off <<= 1){
    int u = (tid >= off) ? lds[tid - off] : 0;
    __syncthreads();
    lds[tid] += u;
    __syncthreads();
  }
  int run = toff[blockIdx.x] + lds[tid] - s;
  #pragma unroll
  for (int j = 0; j < 4; ++j){
    int idx = base + j;
    if (idx < NN){
      rp[idx] = run; run += h[j];
      dinv[idx] = rsqrtf((float)h[j] + 1.f);
    }
  }
}

// ---- chunk-private binning: each block bins its 6250 edges by dst>>6 into its own region ----
// edge packed as (src<<6) | (dst&63)  -- src < 2^17, fits 23 bits
__global__ __launch_bounds__(256) void k_binA(const int* __restrict__ src, const int* __restrict__ dst,
                                              uint* __restrict__ priv, int* __restrict__ seg){
  __shared__ int hist[NB];
  __shared__ int cur[NB];
  __shared__ int scanbuf[256];
  const int c = blockIdx.x, tid = threadIdx.x;
  const size_t e0 = (size_t)c * CHUNK;
  for (int i = tid; i < NB; i += 256) hist[i] = 0;
  __syncthreads();
  for (int i = tid; i < CHUNK; i += 256) atomicAdd(&hist[dst[e0+i] >> 6], 1);
  __syncthreads();
  // in-block exclusive scan over NB entries (7 per thread)
  int loc[7]; int s = 0;
  const int base = tid * 7;
  #pragma unroll
  for (int j = 0; j < 7; ++j){ int idx = base+j; int v = (idx < NB) ? hist[idx] : 0; loc[j] = s; s += v; }
  scanbuf[tid] = s;
  __syncthreads();
  for (int off = 1; off < 256; off <<= 1){
    int u = (tid >= off) ? scanbuf[tid-off] : 0;
    __syncthreads();
    scanbuf[tid] += u;
    __syncthreads();
  }
  const int run = scanbuf[tid] - s;
  #pragma unroll
  for (int j = 0; j < 7; ++j){
    int idx = base+j;
    if (idx < NB){ int st = run + loc[j]; seg[c*(NB+1)+idx] = st; cur[idx] = st; }
  }
  if (tid == 0) seg[c*(NB+1)+NB] = CHUNK;
  __syncthreads();
  for (int i = tid; i < CHUNK; i += 256){
    const uint ss = (uint)src[e0+i], dd = (uint)dst[e0+i];
    const int p = atomicAdd(&cur[dd >> 6], 1);
    priv[(size_t)c*CHUNK + p] = (ss << 6) | (dd & 63u);
  }
}

// per bucket: scatter chunk-private edges directly into dst-node-sorted col via rp cursors.
// writes land in the block's own ~4KB window of col -> no cross-XCD write bouncing.
__global__ __launch_bounds__(256) void k_gathE2(const uint* __restrict__ priv, const int* __restrict__ seg,
                                                const int* __restrict__ rp, int* __restrict__ col){
  __shared__ int cur[64];
  const int b = blockIdx.x, tid = threadIdx.x;
  const int n0 = b * 64;
  if (tid < 64){
    const int idx = n0 + tid;
    cur[tid] = rp[(idx < NN) ? idx : NN];
  }
  __syncthreads();
  const int c = tid;  // thread = chunk
  const int s0 = seg[c*(NB+1) + b], s1 = seg[c*(NB+1) + b + 1];
  const size_t pbase = (size_t)c*CHUNK;
  for (int i = s0; i < s1; ++i){
    const uint e = priv[pbase + i];
    const int p = atomicAdd(&cur[e & 63u], 1);
    col[p] = (int)(e >> 6);
  }
}

// weights -> bf16, concat [sW|bW] as W[n][k], pre-swizzled per 64-k tile image
__global__ __launch_bounds__(256) void k_wprep(const float* __restrict__ sW, const float* __restrict__ bW,
                                               ushort* __restrict__ wimg){
  int idx = blockIdx.x*256 + threadIdx.x;       // ((l*10+q)*128+n)*64+kk
  if (idx >= NL*NKS*128*64) return;
  int kk = idx & 63;
  int n  = (idx >> 6) & 127;
  int q  = (idx >> 13) % NKS;
  int l  = idx / (NKS*128*64);
  int kg = q*64 + kk;
  float v = (kg < KSPL) ? sW[((size_t)l*FEAT + n)*KSPL + kg]
                        : bW[((size_t)l*FEAT + n)*FEAT + (kg - KSPL)];
  size_t tile = ((size_t)l*NKS + q) * (128*64);
  uint byte_in_row = ((uint)(kk*2)) ^ (((uint)(n & 7)) << 4);
  wimg[tile + (size_t)n*64 + (byte_in_row >> 1)] = f2bf(v);
}

// ---------------- FKAN transform: fused LN + RBF + MFMA GEMM ----------------
template <typename TIn>
__global__ __launch_bounds__(256) void k_fkan(
    const TIn* __restrict__ xin,            // [NN][128] fp32 or bf16(ushort)
    const ushort* __restrict__ wimg,        // this layer's pre-swizzled image (10*8192 ushorts)
    const float* __restrict__ ln_s, const float* __restrict__ ln_b,
    const float* __restrict__ sb, const float* __restrict__ bb,
    const float* __restrict__ dinv,
    ushort* __restrict__ hprime)
{
  __shared__ char zb[64*256];        // z bf16 [64][128], xor-swizzled rows
  __shared__ char sA[2*8192];        // silu(x) A-tiles for q=8,9  [64][64] bf16 swizzled
  __shared__ char At[8192];          // basis A-tile [64][64] bf16 swizzled
  __shared__ char Bt[16384];         // B tile [128 n][64 k] bf16 swizzled
  __shared__ float lnS[128], lnB[128], sbias[128];

  const int tid  = threadIdx.x;
  const int lane = tid & 63, wv = tid >> 6;
  const int node0 = blockIdx.x * BM;

  if (tid < 128){ lnS[tid] = ln_s[tid]; lnB[tid] = ln_b[tid]; sbias[tid] = sb[tid] + bb[tid]; }

  // ---- layernorm phase: 4 threads per node ----
  const int lm = tid >> 2, part = tid & 3;
  const int node = node0 + lm;
  float xv[32];
  if (node < NN){
    if constexpr (sizeof(TIn) == 4){
      const float4* xr = (const float4*)((const float*)xin + (size_t)node*FEAT + part*32);
      #pragma unroll
      for (int j = 0; j < 8; ++j){ float4 v = xr[j]; xv[4*j]=v.x; xv[4*j+1]=v.y; xv[4*j+2]=v.z; xv[4*j+3]=v.w; }
    } else {
      const uint4* xr = (const uint4*)((const ushort*)xin + (size_t)node*FEAT + part*32);
      #pragma unroll
      for (int j = 0; j < 4; ++j){
        uint4 v = xr[j];
        uint w0=v.x, w1=v.y, w2=v.z, w3=v.w;
        xv[8*j+0]=bf2f((ushort)(w0&0xffff)); xv[8*j+1]=bf2f((ushort)(w0>>16));
        xv[8*j+2]=bf2f((ushort)(w1&0xffff)); xv[8*j+3]=bf2f((ushort)(w1>>16));
        xv[8*j+4]=bf2f((ushort)(w2&0xffff)); xv[8*j+5]=bf2f((ushort)(w2>>16));
        xv[8*j+6]=bf2f((ushort)(w3&0xffff)); xv[8*j+7]=bf2f((ushort)(w3>>16));
      }
    }
  } else {
    #pragma unroll
    for (int j = 0; j < 32; ++j) xv[j] = 0.f;
  }
  float s1 = 0.f, s2 = 0.f;
  #pragma unroll
  for (int j = 0; j < 32; ++j){ s1 += xv[j]; s2 += xv[j]*xv[j]; }
  s1 += __shfl_xor(s1, 1); s2 += __shfl_xor(s2, 1);
  s1 += __shfl_xor(s1, 2); s2 += __shfl_xor(s2, 2);
  const float mean = s1 * (1.f/128.f);
  const float var  = s2 * (1.f/128.f) - mean*mean;
  const float rs   = rsqrtf(var + 1e-5f);
  __syncthreads();                       // lnS/lnB staged
  {
    const uint swl = ((uint)(lm & 7)) << 4;
    #pragma unroll
    for (int j = 0; j < 32; j += 2){
      const int f = part*32 + j;
      float z0 = (xv[j]   - mean)*rs*lnS[f]   + lnB[f];
      float z1 = (xv[j+1] - mean)*rs*lnS[f+1] + lnB[f+1];
      *(uint*)(zb + lm*256 + (((uint)(f*2)) ^ swl)) = (uint)f2bf(z0) | ((uint)f2bf(z1) << 16);
      float u0 = fsilu(xv[j]), u1 = fsilu(xv[j+1]);
      const int qp = f >> 6, kk = f & 63;
      *(uint*)(sA + qp*8192 + lm*128 + (((uint)(kk*2)) ^ swl)) = (uint)f2bf(u0) | ((uint)f2bf(u1) << 16);
    }
  }
  __syncthreads();                       // zb, sA ready

  // ---- MFMA K-loop ----
  const int l15 = lane & 15, l4h = lane >> 4;
  const int wm = wv >> 1, wn = wv & 1;
  floatx4 acc[2][4];
  #pragma unroll
  for (int mr = 0; mr < 2; ++mr)
    #pragma unroll
    for (int nr = 0; nr < 4; ++nr){ floatx4 z4 = {0.f,0.f,0.f,0.f}; acc[mr][nr] = z4; }

  int rowA[2]; uint swA[2];
  #pragma unroll
  for (int mr = 0; mr < 2; ++mr){ rowA[mr] = wm*32 + mr*16 + l15; swA[mr] = ((uint)(rowA[mr] & 7)) << 4; }
  int colB[4]; uint swB[4];
  #pragma unroll
  for (int nr = 0; nr < 4; ++nr){ colB[nr] = wn*64 + nr*16 + l15; swB[nr] = ((uint)(colB[nr] & 7)) << 4; }

  for (int q = 0; q < NKS; ++q){
    // stage B tile (linear copy of pre-swizzled image)
    {
      const short8* gs = (const short8*)(wimg + (size_t)q*8192);
      short8* lsd = (short8*)Bt;
      lsd[tid      ] = gs[tid      ];
      lsd[tid + 256] = gs[tid + 256];
      lsd[tid + 512] = gs[tid + 512];
      lsd[tid + 768] = gs[tid + 768];
    }
    const char* Ab;
    if (q < 8){
      // generate basis A-tile: thread -> row (tid&63), 16 k's starting at (tid>>6)*16
      const int am = tid & 63, aw = tid >> 6;
      const uint sws = ((uint)(am & 7)) << 4;
      const int f0 = q*16 + aw*4;
      uint2 zz = *(const uint2*)(zb + am*256 + (((uint)(f0*2)) ^ sws));
      float zf[4];
      zf[0] = bf2f((ushort)(zz.x & 0xffff)); zf[1] = bf2f((ushort)(zz.x >> 16));
      zf[2] = bf2f((ushort)(zz.y & 0xffff)); zf[3] = bf2f((ushort)(zz.y >> 16));
      ushort e[16];
      #pragma unroll
      for (int fi = 0; fi < 4; ++fi)
        #pragma unroll
        for (int g = 0; g < 4; ++g){
          float t = (zf[fi] - (-2.f + (4.f/3.f)*(float)g)) * 0.75f;
          e[fi*4+g] = f2bf(__expf(-t*t));
        }
      short8 p0, p1;
      #pragma unroll
      for (int i = 0; i < 8; ++i){ p0[i] = (short)e[i]; p1[i] = (short)e[8+i]; }
      *(short8*)(At + am*128 + (((uint)(aw*32))      ^ sws)) = p0;
      *(short8*)(At + am*128 + (((uint)(aw*32 + 16)) ^ sws)) = p1;
      Ab = At;
    } else {
      Ab = sA + (q - 8)*8192;
    }
    __syncthreads();
    #pragma unroll
    for (int ks = 0; ks < 2; ++ks){
      const uint kb = (uint)(ks*64 + l4h*16);
      short8 af[2], bfr[4];
      #pragma unroll
      for (int mr = 0; mr < 2; ++mr)
        af[mr] = *(const short8*)(Ab + rowA[mr]*128 + (kb ^ swA[mr]));
      #pragma unroll
      for (int nr = 0; nr < 4; ++nr)
        bfr[nr] = *(const short8*)(Bt + colB[nr]*128 + (kb ^ swB[nr]));
      #pragma unroll
      for (int mr = 0; mr < 2; ++mr)
        #pragma unroll
        for (int nr = 0; nr < 4; ++nr)
          acc[mr][nr] = __builtin_amdgcn_mfma_f32_16x16x32_bf16(af[mr], bfr[nr], acc[mr][nr], 0, 0, 0);
    }
    __syncthreads();
  }

  // ---- epilogue: h' = dinv * (acc + bias), bf16 store ----
  #pragma unroll
  for (int mr = 0; mr < 2; ++mr){
    const int rbase = node0 + wm*32 + mr*16 + l4h*4;
    float dvv[4];
    #pragma unroll
    for (int j = 0; j < 4; ++j) dvv[j] = (rbase + j < NN) ? dinv[rbase + j] : 0.f;
    #pragma unroll
    for (int nr = 0; nr < 4; ++nr){
      const int cf = wn*64 + nr*16 + l15;
      const float sv = sbias[cf];
      #pragma unroll
      for (int j = 0; j < 4; ++j){
        const int r = rbase + j;
        if (r < NN) hprime[(size_t)r*FEAT + cf] = f2bf(dvv[j]*(acc[mr][nr][j] + sv));
      }
    }
  }
}

// ---------------- CSR aggregation + silu + bias (one wave per dst node, register accum) ----------------
__global__ __launch_bounds__(256) void k_aggD(
    const ushort* __restrict__ hprime, const int* __restrict__ rp,
    const int* __restrict__ col, const float* __restrict__ dinv,
    const float* __restrict__ gb, ushort* __restrict__ xout)
{
  const int wv = threadIdx.x >> 6, lane = threadIdx.x & 63;
  const int d = blockIdx.x*4 + wv;
  if (d >= NN) return;
  const uint* h2 = (const uint*)hprime;
  const uint v = h2[(size_t)d*64 + lane];
  float a0 = bf2f((ushort)(v & 0xffff)), a1 = bf2f((ushort)(v >> 16));
  const int j0 = rp[d], j1 = rp[d+1];
  int j = j0;
  for (; j + 3 < j1; j += 4){
    const int s0 = col[j], s1c = col[j+1], s2c = col[j+2], s3c = col[j+3];
    const uint w0 = h2[(size_t)s0*64 + lane];
    const uint w1 = h2[(size_t)s1c*64 + lane];
    const uint w2 = h2[(size_t)s2c*64 + lane];
    const uint w3 = h2[(size_t)s3c*64 + lane];
    a0 += bf2f((ushort)(w0 & 0xffff)) + bf2f((ushort)(w1 & 0xffff))
        + bf2f((ushort)(w2 & 0xffff)) + bf2f((ushort)(w3 & 0xffff));
    a1 += bf2f((ushort)(w0 >> 16)) + bf2f((ushort)(w1 >> 16))
        + bf2f((ushort)(w2 >> 16)) + bf2f((ushort)(w3 >> 16));
  }
  for (; j < j1; ++j){
    const int s = col[j];
    const uint w = h2[(size_t)s*64 + lane];
    a0 += bf2f((ushort)(w & 0xffff)); a1 += bf2f((ushort)(w >> 16));
  }
  const float dv = dinv[d];
  const float2 b2 = *(const float2*)(gb + 2*lane);
  a0 = fsilu(dv*a0 + b2.x);
  a1 = fsilu(dv*a1 + b2.y);
  ((uint*)xout)[(size_t)d*64 + lane] = (uint)f2bf(a0) | ((uint)f2bf(a1) << 16);
}

// ---------------- pooling (sorted batch) ----------------
__global__ __launch_bounds__(128) void k_pool(const ushort* __restrict__ x,
                                              const int* __restrict__ batch,
                                              float* __restrict__ pooled,
                                              float* __restrict__ cnt, int n){
  const int f = threadIdx.x;
  const int start = blockIdx.x * 64;
  const int end   = min(start + 64, n);
  if (start >= end) return;
  int cur = batch[start];
  float acc = 0.f, c = 0.f;
  for (int i = start; i < end; ++i){
    const int b = batch[i];
    if (b != cur){
      atomicAdd(&pooled[(size_t)cur*FEAT + f], acc);
      if (f == 0) atomicAdd(&cnt[cur], c);
      cur = b; acc = 0.f; c = 0.f;
    }
    acc += bf2f(x[(size_t)i*FEAT + f]);
    c += 1.f;
  }
  atomicAdd(&pooled[(size_t)cur*FEAT + f], acc);
  if (f == 0) atomicAdd(&cnt[cur], c);
}

__global__ __launch_bounds__(128) void k_pool_div(float* __restrict__ pooled,
                                                  const float* __restrict__ cnt){
  const int g = blockIdx.x, f = threadIdx.x;
  pooled[(size_t)g*FEAT + f] /= fmaxf(cnt[g], 1.f);
}

// ---------------- readout FastKAN (128 -> 10) + log_softmax ----------------
__global__ __launch_bounds__(128) void k_readout(const float* __restrict__ pooled,
    const float* __restrict__ ln_s, const float* __restrict__ ln_b,
    const float* __restrict__ sW, const float* __restrict__ sb,
    const float* __restrict__ bW, const float* __restrict__ bb,
    float* __restrict__ out){
  __shared__ float cb[KSPL + FEAT];
  __shared__ float wred[2][2];
  __shared__ float outv[NCLS];
  const int tid = threadIdx.x, lane = tid & 63, wave = tid >> 6;
  const int g = blockIdx.x;

  const float xvv = pooled[(size_t)g*FEAT + tid];
  float s1 = xvv, s2 = xvv*xvv;
  #pragma unroll
  for (int off = 32; off; off >>= 1){ s1 += __shfl_down(s1, off); s2 += __shfl_down(s2, off); }
  if (lane == 0){ wred[wave][0] = s1; wred[wave][1] = s2; }
  __syncthreads();
  const float m   = (wred[0][0] + wred[1][0]) * (1.f/FEAT);
  const float var = (wred[0][1] + wred[1][1]) * (1.f/FEAT) - m*m;
  const float rs  = rsqrtf(var + 1e-5f);
  const float z   = (xvv - m) * rs * ln_s[tid] + ln_b[tid];
  #pragma unroll
  for (int gg = 0; gg < GQ; ++gg){
    const float t = (z - (-2.f + (4.f/3.f)*(float)gg)) * 0.75f;
    cb[tid*GQ + gg] = __expf(-t*t);
  }
  cb[KSPL + tid] = fsilu(xvv);
  __syncthreads();

  if (tid < NCLS){
    const float* wr = sW + (size_t)tid*KSPL;
    const float* br = bW + (size_t)tid*FEAT;
    float acc = sb[tid] + bb[tid];
    for (int k = 0; k < KSPL; ++k) acc += cb[k] * wr[k];
    for (int k = 0; k < FEAT; ++k) acc += cb[KSPL + k] * br[k];
    outv[tid] = acc;
  }
  __syncthreads();
  if (tid == 0){
    float mx = -1e30f;
    for (int o = 0; o < NCLS; ++o) mx = fmaxf(mx, outv[o]);
    float se = 0.f;
    for (int o = 0; o < NCLS; ++o) se += __expf(outv[o] - mx);
    const float lse = mx + logf(se);
    for (int o = 0; o < NCLS; ++o) out[(size_t)g*NCLS + o] = outv[o] - lse;
  }
}

extern "C" void kernel_launch(void* const* d_in, const int* in_sizes, int n_in,
                              void* d_out, int out_size, void* d_ws, size_t ws_size,
                              hipStream_t stream) {
  const float* x     = (const float*)d_in[0];
  const int*   edge  = (const int*)d_in[1];
  const int*   batch = (const int*)d_in[2];
  const float* ln_s  = (const float*)d_in[3];
  const float* ln_b  = (const float*)d_in[4];
  const float* sW    = (const float*)d_in[5];
  const float* sb    = (const float*)d_in[6];
  const float* bW    = (const float*)d_in[7];
  const float* bb    = (const float*)d_in[8];
  const float* gcn_b = (const float*)d_in[9];
  const float* ro_ln_s = (const float*)d_in[10];
  const float* ro_ln_b = (const float*)d_in[11];
  const float* ro_sW   = (const float*)d_in[12];
  const float* ro_sb   = (const float*)d_in[13];
  const float* ro_bW   = (const float*)d_in[14];
  const float* ro_bb   = (const float*)d_in[15];
  float* out = (float*)d_out;

  const int* src = edge;
  const int* dst = edge + NE;

  char* W = (char*)d_ws;
  size_t off = 0;
  auto alloc = [&](size_t bytes){ size_t r = off; off += (bytes + 1023) & ~((size_t)1023); return r; };
  float*  dinv   = (float*) (W + alloc((size_t)NN*4));
  ushort* wimg   = (ushort*)(W + alloc((size_t)NL*NKS*8192*2));
  int*    hist   = (int*)   (W + alloc((size_t)NN*4));
  int*    rp     = (int*)   (W + alloc((size_t)(NN+1)*4));
  int*    tsum   = (int*)   (W + alloc((size_t)NT*4));
  int*    toff   = (int*)   (W + alloc((size_t)NT*4));
  uint*   priv   = (uint*)  (W + alloc((size_t)NE*4));
  int*    seg    = (int*)   (W + alloc((size_t)NCHUNK*(NB+1)*4));
  int*    col    = (int*)   (W + alloc((size_t)NE*4));
  ushort* hprime = (ushort*)(W + alloc((size_t)NN*FEAT*2));
  ushort* xcur   = (ushort*)(W + alloc((size_t)NN*FEAT*2));
  float*  pooled = (float*) (W + alloc((size_t)(NGR*FEAT + NGR)*4));
  float*  cnt    = pooled + NGR*FEAT;

  // degree norm + CSR build (layer-invariant): hist -> scan -> chunk-bin -> bucket scatter
  k_zero_i<<<(NN+255)/256, 256, 0, stream>>>(hist, NN);
  k_zero_f<<<(NGR*FEAT+NGR+255)/256, 256, 0, stream>>>(pooled, NGR*FEAT + NGR);
  k_hist<<<(NE+255)/256, 256, 0, stream>>>(dst, hist, NE);
  k_scan_a<<<NT, 256, 0, stream>>>(hist, tsum);
  k_scan_b<<<1, 128, 0, stream>>>(tsum, toff, rp + NN);
  k_scan_c<<<NT, 256, 0, stream>>>(hist, toff, rp, dinv);
  k_binA<<<NCHUNK, 256, 0, stream>>>(src, dst, priv, seg);
  k_gathE2<<<NB, 256, 0, stream>>>(priv, seg, rp, col);
  k_wprep<<<(NL*NKS*128*64 + 255)/256, 256, 0, stream>>>(sW, bW, wimg);

  const int fkan_grid = (NN + BM - 1) / BM;
  for (int l = 0; l < NL; ++l){
    const ushort* wl = wimg + (size_t)l*NKS*8192;
    if (l == 0)
      k_fkan<float><<<fkan_grid, 256, 0, stream>>>(x, wl,
          ln_s + l*FEAT, ln_b + l*FEAT, sb + l*FEAT, bb + l*FEAT, dinv, hprime);
    else
      k_fkan<ushort><<<fkan_grid, 256, 0, stream>>>(xcur, wl,
          ln_s + l*FEAT, ln_b + l*FEAT, sb + l*FEAT, bb + l*FEAT, dinv, hprime);
    k_aggD<<<(NN+3)/4, 256, 0, stream>>>(hprime, rp, col, dinv, gcn_b + l*FEAT, xcur);
  }

  k_pool<<<(NN+63)/64, 128, 0, stream>>>(xcur, batch, pooled, cnt, NN);
  k_pool_div<<<NGR, 128, 0, stream>>>(pooled, cnt);
  k_readout<<<NGR, 128, 0, stream>>>(pooled, ro_ln_s, ro_ln_b,
                                     ro_sW, ro_sb, ro_bW, ro_bb, out);
}

// Round 7
// 561.826 us; speedup vs baseline: 6.9296x; 1.0482x over previous
//
#include <hip/hip_runtime.h>
#include <math.h>

#define NN     100000
#define NE     1600000
#define FEAT   128
#define GQ     4
#define NL     3
#define NGR    64
#define NCLS   10
#define KSPL   512
#define NKS    10            /* K-steps of 64 (640 total) */
#define BM     64
#define NB     1563          /* dst buckets of 64 nodes: ceil(NN/64) */
#define NCHUNK 256
#define CHUNK  6250          /* NE / NCHUNK */
#define TILE   1024
#define NT     ((NN + TILE - 1) / TILE)   /* 98 scan tiles */
#define WSTRIDE (NKS*2*4*2*512)           /* 81920 ushorts per layer */

typedef __attribute__((ext_vector_type(8))) short short8;
typedef __attribute__((ext_vector_type(4))) float floatx4;

__device__ __forceinline__ float fsilu(float x){ return x / (1.f + __expf(-x)); }
__device__ __forceinline__ ushort f2bf(float f){
  uint u = __builtin_bit_cast(uint, f);
  return (ushort)((u + 0x7FFFu + ((u >> 16) & 1u)) >> 16);
}
__device__ __forceinline__ float bf2f(ushort h){ return __builtin_bit_cast(float, ((uint)h) << 16); }

// ---------------- small utility kernels ----------------
__global__ __launch_bounds__(256) void k_zero_i(int* __restrict__ p, int n){
  int i = blockIdx.x*256 + threadIdx.x; if (i < n) p[i] = 0;
}
__global__ __launch_bounds__(256) void k_zero_f(float* __restrict__ p, int n){
  int i = blockIdx.x*256 + threadIdx.x; if (i < n) p[i] = 0.f;
}
__global__ __launch_bounds__(256) void k_hist(const int* __restrict__ dst, int* __restrict__ hist, int ne){
  int e = blockIdx.x*256 + threadIdx.x; if (e < ne) atomicAdd(&hist[dst[e]], 1);
}

// ---- hierarchical exclusive scan over hist[NN] -> rp, dinv ----
__global__ __launch_bounds__(256) void k_scan_a(const int* __restrict__ hist, int* __restrict__ tsum){
  __shared__ int red[4];
  const int base = blockIdx.x * TILE;
  int s = 0;
  #pragma unroll
  for (int j = 0; j < 4; ++j){
    int idx = base + threadIdx.x + j*256;
    if (idx < NN) s += hist[idx];
  }
  #pragma unroll
  for (int off = 32; off; off >>= 1) s += __shfl_down(s, off);
  if ((threadIdx.x & 63) == 0) red[threadIdx.x >> 6] = s;
  __syncthreads();
  if (threadIdx.x == 0) tsum[blockIdx.x] = red[0] + red[1] + red[2] + red[3];
}

__global__ __launch_bounds__(128) void k_scan_b(const int* __restrict__ tsum,
                                                int* __restrict__ toff, int* __restrict__ rpN){
  __shared__ int lds[128];
  const int tid = threadIdx.x;
  int v = (tid < NT) ? tsum[tid] : 0;
  lds[tid] = v; __syncthreads();
  for (int off = 1; off < 128; off <<= 1){
    int u = (tid >= off) ? lds[tid - off] : 0;
    __syncthreads();
    lds[tid] += u;
    __syncthreads();
  }
  if (tid < NT) toff[tid] = lds[tid] - v;
  if (tid == NT - 1) *rpN = lds[tid];
}

__global__ __launch_bounds__(256) void k_scan_c(const int* __restrict__ hist,
                                                const int* __restrict__ toff,
                                                int* __restrict__ rp,
                                                float* __restrict__ dinv){
  __shared__ int lds[256];
  const int tid = threadIdx.x;
  const int base = blockIdx.x * TILE + tid*4;
  int h[4]; int s = 0;
  #pragma unroll
  for (int j = 0; j < 4; ++j){ int idx = base + j; h[j] = (idx < NN) ? hist[idx] : 0; s += h[j]; }
  lds[tid] = s; __syncthreads();
  for (int off = 1; off < 256; off <<= 1){
    int u = (tid >= off) ? lds[tid - off] : 0;
    __syncthreads();
    lds[tid] += u;
    __syncthreads();
  }
  int run = toff[blockIdx.x] + lds[tid] - s;
  #pragma unroll
  for (int j = 0; j < 4; ++j){
    int idx = base + j;
    if (idx < NN){
      rp[idx] = run; run += h[j];
      dinv[idx] = rsqrtf((float)h[j] + 1.f);
    }
  }
}

// ---- chunk-private binning: each block bins its 6250 edges by dst>>6 into its own region ----
// edge packed as (src<<6) | (dst&63)
__global__ __launch_bounds__(256) void k_binA(const int* __restrict__ src, const int* __restrict__ dst,
                                              uint* __restrict__ priv, int* __restrict__ seg){
  __shared__ int hist[NB];
  __shared__ int cur[NB];
  __shared__ int scanbuf[256];
  const int c = blockIdx.x, tid = threadIdx.x;
  const size_t e0 = (size_t)c * CHUNK;
  for (int i = tid; i < NB; i += 256) hist[i] = 0;
  __syncthreads();
  for (int i = tid; i < CHUNK; i += 256) atomicAdd(&hist[dst[e0+i] >> 6], 1);
  __syncthreads();
  int loc[7]; int s = 0;
  const int base = tid * 7;
  #pragma unroll
  for (int j = 0; j < 7; ++j){ int idx = base+j; int v = (idx < NB) ? hist[idx] : 0; loc[j] = s; s += v; }
  scanbuf[tid] = s;
  __syncthreads();
  for (int off = 1; off < 256; off <<= 1){
    int u = (tid >= off) ? scanbuf[tid-off] : 0;
    __syncthreads();
    scanbuf[tid] += u;
    __syncthreads();
  }
  const int run = scanbuf[tid] - s;
  #pragma unroll
  for (int j = 0; j < 7; ++j){
    int idx = base+j;
    if (idx < NB){ int st = run + loc[j]; seg[c*(NB+1)+idx] = st; cur[idx] = st; }
  }
  if (tid == 0) seg[c*(NB+1)+NB] = CHUNK;
  __syncthreads();
  for (int i = tid; i < CHUNK; i += 256){
    const uint ss = (uint)src[e0+i], dd = (uint)dst[e0+i];
    const int p = atomicAdd(&cur[dd >> 6], 1);
    priv[(size_t)c*CHUNK + p] = (ss << 6) | (dd & 63u);
  }
}

// per bucket: scatter chunk-private edges into dst-node-sorted col via rp cursors
__global__ __launch_bounds__(256) void k_gathE2(const uint* __restrict__ priv, const int* __restrict__ seg,
                                                const int* __restrict__ rp, int* __restrict__ col){
  __shared__ int cur[64];
  const int b = blockIdx.x, tid = threadIdx.x;
  const int n0 = b * 64;
  if (tid < 64){
    const int idx = n0 + tid;
    cur[tid] = rp[(idx < NN) ? idx : NN];
  }
  __syncthreads();
  const int c = tid;
  const int s0 = seg[c*(NB+1) + b], s1 = seg[c*(NB+1) + b + 1];
  const size_t pbase = (size_t)c*CHUNK;
  for (int i = s0; i < s1; ++i){
    const uint e = priv[pbase + i];
    const int p = atomicAdd(&cur[e & 63u], 1);
    col[p] = (int)(e >> 6);
  }
}

// weights -> bf16 in per-lane MFMA fragment layout:
// wimg[(((l*10+q)*2+wn)*4+nr)*2+ks][lane*8+j] = W[col][k],
//   col = wn*64+nr*16+(lane&15), k = q*64+ks*32+(lane>>4)*8+j
__global__ __launch_bounds__(256) void k_wprep(const float* __restrict__ sW, const float* __restrict__ bW,
                                               ushort* __restrict__ wimg){
  int idx = blockIdx.x*256 + threadIdx.x;
  if (idx >= NL*WSTRIDE) return;
  const int j    = idx & 7;
  const int lane = (idx >> 3) & 63;
  const int ks   = (idx >> 9) & 1;
  const int nr   = (idx >> 10) & 3;
  const int wn   = (idx >> 12) & 1;
  const int qq   = (idx >> 13) % NKS;
  const int l    = idx / (NKS << 13);
  const int colc = wn*64 + nr*16 + (lane & 15);
  const int kg   = qq*64 + ks*32 + (lane >> 4)*8 + j;
  const float v  = (kg < KSPL) ? sW[((size_t)l*FEAT + colc)*KSPL + kg]
                               : bW[((size_t)l*FEAT + colc)*FEAT + (kg - KSPL)];
  wimg[idx] = f2bf(v);
}

// ---------------- FKAN transform: LN + in-register RBF + MFMA, barrier-free K-loop ----------------
template <typename TIn>
__global__ __launch_bounds__(256) void k_fkan(
    const TIn* __restrict__ xin,            // [NN][128] fp32 or bf16(ushort)
    const ushort* __restrict__ wimg,        // this layer's fragment image (81920 ushorts, L2-resident)
    const float* __restrict__ ln_s, const float* __restrict__ ln_b,
    const float* __restrict__ sb, const float* __restrict__ bb,
    const float* __restrict__ dinv,
    ushort* __restrict__ hprime)
{
  __shared__ char zb[64*256];        // z bf16 [64][128], xor-swizzled rows
  __shared__ char zs[64*256];        // silu(x) bf16 [64][128], same swizzle
  __shared__ float lnS[128], lnB[128], sbias[128];

  const int tid  = threadIdx.x;
  const int lane = tid & 63, wv = tid >> 6;
  const int node0 = blockIdx.x * BM;

  if (tid < 128){ lnS[tid] = ln_s[tid]; lnB[tid] = ln_b[tid]; sbias[tid] = sb[tid] + bb[tid]; }

  // ---- layernorm phase: 4 threads per node ----
  const int lm = tid >> 2, part = tid & 3;
  const int node = node0 + lm;
  float xv[32];
  if (node < NN){
    if constexpr (sizeof(TIn) == 4){
      const float4* xr = (const float4*)((const float*)xin + (size_t)node*FEAT + part*32);
      #pragma unroll
      for (int j = 0; j < 8; ++j){ float4 v = xr[j]; xv[4*j]=v.x; xv[4*j+1]=v.y; xv[4*j+2]=v.z; xv[4*j+3]=v.w; }
    } else {
      const uint4* xr = (const uint4*)((const ushort*)xin + (size_t)node*FEAT + part*32);
      #pragma unroll
      for (int j = 0; j < 4; ++j){
        uint4 v = xr[j];
        uint w0=v.x, w1=v.y, w2=v.z, w3=v.w;
        xv[8*j+0]=bf2f((ushort)(w0&0xffff)); xv[8*j+1]=bf2f((ushort)(w0>>16));
        xv[8*j+2]=bf2f((ushort)(w1&0xffff)); xv[8*j+3]=bf2f((ushort)(w1>>16));
        xv[8*j+4]=bf2f((ushort)(w2&0xffff)); xv[8*j+5]=bf2f((ushort)(w2>>16));
        xv[8*j+6]=bf2f((ushort)(w3&0xffff)); xv[8*j+7]=bf2f((ushort)(w3>>16));
      }
    }
  } else {
    #pragma unroll
    for (int j = 0; j < 32; ++j) xv[j] = 0.f;
  }
  float s1 = 0.f, s2 = 0.f;
  #pragma unroll
  for (int j = 0; j < 32; ++j){ s1 += xv[j]; s2 += xv[j]*xv[j]; }
  s1 += __shfl_xor(s1, 1); s2 += __shfl_xor(s2, 1);
  s1 += __shfl_xor(s1, 2); s2 += __shfl_xor(s2, 2);
  const float mean = s1 * (1.f/128.f);
  const float var  = s2 * (1.f/128.f) - mean*mean;
  const float rs   = rsqrtf(var + 1e-5f);
  __syncthreads();                       // lnS/lnB staged
  {
    const uint swl = ((uint)(lm & 7)) << 4;
    #pragma unroll
    for (int j = 0; j < 32; j += 2){
      const int f = part*32 + j;
      float z0 = (xv[j]   - mean)*rs*lnS[f]   + lnB[f];
      float z1 = (xv[j+1] - mean)*rs*lnS[f+1] + lnB[f+1];
      *(uint*)(zb + lm*256 + (((uint)(f*2)) ^ swl)) = (uint)f2bf(z0) | ((uint)f2bf(z1) << 16);
      float u0 = fsilu(xv[j]), u1 = fsilu(xv[j+1]);
      *(uint*)(zs + lm*256 + (((uint)(f*2)) ^ swl)) = (uint)f2bf(u0) | ((uint)f2bf(u1) << 16);
    }
  }
  __syncthreads();                       // zb, zs ready -- last barrier

  // ---- barrier-free MFMA K-loop ----
  const int l15 = lane & 15, l4h = lane >> 4;
  const int wm = wv >> 1, wn = wv & 1;
  floatx4 acc[2][4];
  #pragma unroll
  for (int mr = 0; mr < 2; ++mr)
    #pragma unroll
    for (int nr = 0; nr < 4; ++nr){ floatx4 z4 = {0.f,0.f,0.f,0.f}; acc[mr][nr] = z4; }

  int rowA[2]; uint swA[2];
  #pragma unroll
  for (int mr = 0; mr < 2; ++mr){ rowA[mr] = wm*32 + mr*16 + l15; swA[mr] = ((uint)(rowA[mr] & 7)) << 4; }

  const short8* w8 = (const short8*)wimg;

  for (int q = 0; q < NKS; ++q){
    // load 8 B fragments direct from L2 (coalesced 16B/lane, no LDS, no barrier)
    short8 bfr[4][2];
    const int fbase = (q*2 + wn)*4;
    #pragma unroll
    for (int nr = 0; nr < 4; ++nr)
      #pragma unroll
      for (int ks = 0; ks < 2; ++ks)
        bfr[nr][ks] = w8[(size_t)((fbase + nr)*2 + ks)*64 + lane];

    if (q < 8){
      #pragma unroll
      for (int ks = 0; ks < 2; ++ks)
        #pragma unroll
        for (int mr = 0; mr < 2; ++mr){
          const int f0 = q*16 + ks*8 + l4h*2;
          const uint zz = *(const uint*)(zb + rowA[mr]*256 + (((uint)(f0*2)) ^ swA[mr]));
          const float z0 = bf2f((ushort)(zz & 0xffff)), z1 = bf2f((ushort)(zz >> 16));
          short8 af;
          #pragma unroll
          for (int g = 0; g < 4; ++g){
            const float gc = -2.f + (4.f/3.f)*(float)g;
            const float t0 = (z0 - gc)*0.75f;
            const float t1 = (z1 - gc)*0.75f;
            af[g]   = (short)f2bf(__expf(-t0*t0));
            af[4+g] = (short)f2bf(__expf(-t1*t1));
          }
          #pragma unroll
          for (int nr = 0; nr < 4; ++nr)
            acc[mr][nr] = __builtin_amdgcn_mfma_f32_16x16x32_bf16(af, bfr[nr][ks], acc[mr][nr], 0, 0, 0);
        }
    } else {
      #pragma unroll
      for (int ks = 0; ks < 2; ++ks)
        #pragma unroll
        for (int mr = 0; mr < 2; ++mr){
          const int f0 = (q - 8)*64 + ks*32 + l4h*8;
          const short8 af = *(const short8*)(zs + rowA[mr]*256 + (((uint)(f0*2)) ^ swA[mr]));
          #pragma unroll
          for (int nr = 0; nr < 4; ++nr)
            acc[mr][nr] = __builtin_amdgcn_mfma_f32_16x16x32_bf16(af, bfr[nr][ks], acc[mr][nr], 0, 0, 0);
        }
    }
  }

  // ---- epilogue: h' = dinv * (acc + bias), bf16 store ----
  #pragma unroll
  for (int mr = 0; mr < 2; ++mr){
    const int rbase = node0 + wm*32 + mr*16 + l4h*4;
    float dvv[4];
    #pragma unroll
    for (int j = 0; j < 4; ++j) dvv[j] = (rbase + j < NN) ? dinv[rbase + j] : 0.f;
    #pragma unroll
    for (int nr = 0; nr < 4; ++nr){
      const int cf = wn*64 + nr*16 + l15;
      const float sv = sbias[cf];
      #pragma unroll
      for (int j = 0; j < 4; ++j){
        const int r = rbase + j;
        if (r < NN) hprime[(size_t)r*FEAT + cf] = f2bf(dvv[j]*(acc[mr][nr][j] + sv));
      }
    }
  }
}

// ---------------- CSR aggregation + silu + bias (one wave per dst node, register accum) ----------------
__global__ __launch_bounds__(256) void k_aggD(
    const ushort* __restrict__ hprime, const int* __restrict__ rp,
    const int* __restrict__ col, const float* __restrict__ dinv,
    const float* __restrict__ gb, ushort* __restrict__ xout)
{
  const int wv = threadIdx.x >> 6, lane = threadIdx.x & 63;
  const int d = blockIdx.x*4 + wv;
  if (d >= NN) return;
  const uint* h2 = (const uint*)hprime;
  const uint v = h2[(size_t)d*64 + lane];
  float a0 = bf2f((ushort)(v & 0xffff)), a1 = bf2f((ushort)(v >> 16));
  const int j0 = rp[d], j1 = rp[d+1];
  int j = j0;
  for (; j + 3 < j1; j += 4){
    const int s0 = col[j], s1c = col[j+1], s2c = col[j+2], s3c = col[j+3];
    const uint w0 = h2[(size_t)s0*64 + lane];
    const uint w1 = h2[(size_t)s1c*64 + lane];
    const uint w2 = h2[(size_t)s2c*64 + lane];
    const uint w3 = h2[(size_t)s3c*64 + lane];
    a0 += bf2f((ushort)(w0 & 0xffff)) + bf2f((ushort)(w1 & 0xffff))
        + bf2f((ushort)(w2 & 0xffff)) + bf2f((ushort)(w3 & 0xffff));
    a1 += bf2f((ushort)(w0 >> 16)) + bf2f((ushort)(w1 >> 16))
        + bf2f((ushort)(w2 >> 16)) + bf2f((ushort)(w3 >> 16));
  }
  for (; j < j1; ++j){
    const int s = col[j];
    const uint w = h2[(size_t)s*64 + lane];
    a0 += bf2f((ushort)(w & 0xffff)); a1 += bf2f((ushort)(w >> 16));
  }
  const float dv = dinv[d];
  const float2 b2 = *(const float2*)(gb + 2*lane);
  a0 = fsilu(dv*a0 + b2.x);
  a1 = fsilu(dv*a1 + b2.y);
  ((uint*)xout)[(size_t)d*64 + lane] = (uint)f2bf(a0) | ((uint)f2bf(a1) << 16);
}

// ---------------- pooling (sorted batch) ----------------
__global__ __launch_bounds__(128) void k_pool(const ushort* __restrict__ x,
                                              const int* __restrict__ batch,
                                              float* __restrict__ pooled,
                                              float* __restrict__ cnt, int n){
  const int f = threadIdx.x;
  const int start = blockIdx.x * 64;
  const int end   = min(start + 64, n);
  if (start >= end) return;
  int cur = batch[start];
  float acc = 0.f, c = 0.f;
  for (int i = start; i < end; ++i){
    const int b = batch[i];
    if (b != cur){
      atomicAdd(&pooled[(size_t)cur*FEAT + f], acc);
      if (f == 0) atomicAdd(&cnt[cur], c);
      cur = b; acc = 0.f; c = 0.f;
    }
    acc += bf2f(x[(size_t)i*FEAT + f]);
    c += 1.f;
  }
  atomicAdd(&pooled[(size_t)cur*FEAT + f], acc);
  if (f == 0) atomicAdd(&cnt[cur], c);
}

__global__ __launch_bounds__(128) void k_pool_div(float* __restrict__ pooled,
                                                  const float* __restrict__ cnt){
  const int g = blockIdx.x, f = threadIdx.x;
  pooled[(size_t)g*FEAT + f] /= fmaxf(cnt[g], 1.f);
}

// ---------------- readout FastKAN (128 -> 10) + log_softmax ----------------
__global__ __launch_bounds__(128) void k_readout(const float* __restrict__ pooled,
    const float* __restrict__ ln_s, const float* __restrict__ ln_b,
    const float* __restrict__ sW, const float* __restrict__ sb,
    const float* __restrict__ bW, const float* __restrict__ bb,
    float* __restrict__ out){
  __shared__ float cb[KSPL + FEAT];
  __shared__ float wred[2][2];
  __shared__ float outv[NCLS];
  const int tid = threadIdx.x, lane = tid & 63, wave = tid >> 6;
  const int g = blockIdx.x;

  const float xvv = pooled[(size_t)g*FEAT + tid];
  float s1 = xvv, s2 = xvv*xvv;
  #pragma unroll
  for (int off = 32; off; off >>= 1){ s1 += __shfl_down(s1, off); s2 += __shfl_down(s2, off); }
  if (lane == 0){ wred[wave][0] = s1; wred[wave][1] = s2; }
  __syncthreads();
  const float m   = (wred[0][0] + wred[1][0]) * (1.f/FEAT);
  const float var = (wred[0][1] + wred[1][1]) * (1.f/FEAT) - m*m;
  const float rs  = rsqrtf(var + 1e-5f);
  const float z   = (xvv - m) * rs * ln_s[tid] + ln_b[tid];
  #pragma unroll
  for (int gg = 0; gg < GQ; ++gg){
    const float t = (z - (-2.f + (4.f/3.f)*(float)gg)) * 0.75f;
    cb[tid*GQ + gg] = __expf(-t*t);
  }
  cb[KSPL + tid] = fsilu(xvv);
  __syncthreads();

  if (tid < NCLS){
    const float* wr = sW + (size_t)tid*KSPL;
    const float* br = bW + (size_t)tid*FEAT;
    float acc = sb[tid] + bb[tid];
    for (int k = 0; k < KSPL; ++k) acc += cb[k] * wr[k];
    for (int k = 0; k < FEAT; ++k) acc += cb[KSPL + k] * br[k];
    outv[tid] = acc;
  }
  __syncthreads();
  if (tid == 0){
    float mx = -1e30f;
    for (int o = 0; o < NCLS; ++o) mx = fmaxf(mx, outv[o]);
    float se = 0.f;
    for (int o = 0; o < NCLS; ++o) se += __expf(outv[o] - mx);
    const float lse = mx + logf(se);
    for (int o = 0; o < NCLS; ++o) out[(size_t)g*NCLS + o] = outv[o] - lse;
  }
}

extern "C" void kernel_launch(void* const* d_in, const int* in_sizes, int n_in,
                              void* d_out, int out_size, void* d_ws, size_t ws_size,
                              hipStream_t stream) {
  const float* x     = (const float*)d_in[0];
  const int*   edge  = (const int*)d_in[1];
  const int*   batch = (const int*)d_in[2];
  const float* ln_s  = (const float*)d_in[3];
  const float* ln_b  = (const float*)d_in[4];
  const float* sW    = (const float*)d_in[5];
  const float* sb    = (const float*)d_in[6];
  const float* bW    = (const float*)d_in[7];
  const float* bb    = (const float*)d_in[8];
  const float* gcn_b = (const float*)d_in[9];
  const float* ro_ln_s = (const float*)d_in[10];
  const float* ro_ln_b = (const float*)d_in[11];
  const float* ro_sW   = (const float*)d_in[12];
  const float* ro_sb   = (const float*)d_in[13];
  const float* ro_bW   = (const float*)d_in[14];
  const float* ro_bb   = (const float*)d_in[15];
  float* out = (float*)d_out;

  const int* src = edge;
  const int* dst = edge + NE;

  char* W = (char*)d_ws;
  size_t off = 0;
  auto alloc = [&](size_t bytes){ size_t r = off; off += (bytes + 1023) & ~((size_t)1023); return r; };
  float*  dinv   = (float*) (W + alloc((size_t)NN*4));
  ushort* wimg   = (ushort*)(W + alloc((size_t)NL*WSTRIDE*2));
  int*    hist   = (int*)   (W + alloc((size_t)NN*4));
  int*    rp     = (int*)   (W + alloc((size_t)(NN+1)*4));
  int*    tsum   = (int*)   (W + alloc((size_t)NT*4));
  int*    toff   = (int*)   (W + alloc((size_t)NT*4));
  uint*   priv   = (uint*)  (W + alloc((size_t)NE*4));
  int*    seg    = (int*)   (W + alloc((size_t)NCHUNK*(NB+1)*4));
  int*    col    = (int*)   (W + alloc((size_t)NE*4));
  ushort* hprime = (ushort*)(W + alloc((size_t)NN*FEAT*2));
  ushort* xcur   = (ushort*)(W + alloc((size_t)NN*FEAT*2));
  float*  pooled = (float*) (W + alloc((size_t)(NGR*FEAT + NGR)*4));
  float*  cnt    = pooled + NGR*FEAT;

  // degree norm + CSR build (layer-invariant)
  k_zero_i<<<(NN+255)/256, 256, 0, stream>>>(hist, NN);
  k_zero_f<<<(NGR*FEAT+NGR+255)/256, 256, 0, stream>>>(pooled, NGR*FEAT + NGR);
  k_hist<<<(NE+255)/256, 256, 0, stream>>>(dst, hist, NE);
  k_scan_a<<<NT, 256, 0, stream>>>(hist, tsum);
  k_scan_b<<<1, 128, 0, stream>>>(tsum, toff, rp + NN);
  k_scan_c<<<NT, 256, 0, stream>>>(hist, toff, rp, dinv);
  k_binA<<<NCHUNK, 256, 0, stream>>>(src, dst, priv, seg);
  k_gathE2<<<NB, 256, 0, stream>>>(priv, seg, rp, col);
  k_wprep<<<(NL*WSTRIDE + 255)/256, 256, 0, stream>>>(sW, bW, wimg);

  const int fkan_grid = (NN + BM - 1) / BM;
  for (int l = 0; l < NL; ++l){
    const ushort* wl = wimg + (size_t)l*WSTRIDE;
    if (l == 0)
      k_fkan<float><<<fkan_grid, 256, 0, stream>>>(x, wl,
          ln_s + l*FEAT, ln_b + l*FEAT, sb + l*FEAT, bb + l*FEAT, dinv, hprime);
    else
      k_fkan<ushort><<<fkan_grid, 256, 0, stream>>>(xcur, wl,
          ln_s + l*FEAT, ln_b + l*FEAT, sb + l*FEAT, bb + l*FEAT, dinv, hprime);
    k_aggD<<<(NN+3)/4, 256, 0, stream>>>(hprime, rp, col, dinv, gcn_b + l*FEAT, xcur);
  }

  k_pool<<<(NN+63)/64, 128, 0, stream>>>(xcur, batch, pooled, cnt, NN);
  k_pool_div<<<NGR, 128, 0, stream>>>(pooled, cnt);
  k_readout<<<NGR, 128, 0, stream>>>(pooled, ro_ln_s, ro_ln_b,
                                     ro_sW, ro_sb, ro_bW, ro_bb, out);
}

// Round 8
// 521.399 us; speedup vs baseline: 7.4669x; 1.0775x over previous
//
#include <hip/hip_runtime.h>
#include <math.h>

#define NN     100000
#define NE     1600000
#define FEAT   128
#define GQ     4
#define NL     3
#define NGR    64
#define NCLS   10
#define KSPL   512
#define NKS    10            /* K-steps of 64 (640 total) */
#define BM     64
#define NB     1563          /* dst buckets of 64 nodes: ceil(NN/64) */
#define NCHUNK 256
#define CHUNK  6250          /* NE / NCHUNK */
#define TILE   1024
#define NT     ((NN + TILE - 1) / TILE)   /* 98 scan tiles */
#define WSTRIDE (NKS*8*2*512)             /* 81920 ushorts per layer */

typedef __attribute__((ext_vector_type(8))) short short8;
typedef __attribute__((ext_vector_type(4))) float floatx4;
typedef __attribute__((ext_vector_type(4))) uint uintx4;

__device__ __forceinline__ float fsilu(float x){ return x / (1.f + __expf(-x)); }
__device__ __forceinline__ ushort f2bf(float f){
  uint u = __builtin_bit_cast(uint, f);
  return (ushort)((u + 0x7FFFu + ((u >> 16) & 1u)) >> 16);
}
__device__ __forceinline__ float bf2f(ushort h){ return __builtin_bit_cast(float, ((uint)h) << 16); }
__device__ __forceinline__ uint bu(float f){ return __builtin_bit_cast(uint, f); }

// ---------------- small utility kernels ----------------
__global__ __launch_bounds__(256) void k_zero_i(int* __restrict__ p, int n){
  int i = blockIdx.x*256 + threadIdx.x; if (i < n) p[i] = 0;
}
__global__ __launch_bounds__(256) void k_zero_f(float* __restrict__ p, int n){
  int i = blockIdx.x*256 + threadIdx.x; if (i < n) p[i] = 0.f;
}
__global__ __launch_bounds__(256) void k_hist(const int* __restrict__ dst, int* __restrict__ hist, int ne){
  int e = blockIdx.x*256 + threadIdx.x; if (e < ne) atomicAdd(&hist[dst[e]], 1);
}

// ---- hierarchical exclusive scan over hist[NN] -> rp, dinv ----
__global__ __launch_bounds__(256) void k_scan_a(const int* __restrict__ hist, int* __restrict__ tsum){
  __shared__ int red[4];
  const int base = blockIdx.x * TILE;
  int s = 0;
  #pragma unroll
  for (int j = 0; j < 4; ++j){
    int idx = base + threadIdx.x + j*256;
    if (idx < NN) s += hist[idx];
  }
  #pragma unroll
  for (int off = 32; off; off >>= 1) s += __shfl_down(s, off);
  if ((threadIdx.x & 63) == 0) red[threadIdx.x >> 6] = s;
  __syncthreads();
  if (threadIdx.x == 0) tsum[blockIdx.x] = red[0] + red[1] + red[2] + red[3];
}

__global__ __launch_bounds__(128) void k_scan_b(const int* __restrict__ tsum,
                                                int* __restrict__ toff, int* __restrict__ rpN){
  __shared__ int lds[128];
  const int tid = threadIdx.x;
  int v = (tid < NT) ? tsum[tid] : 0;
  lds[tid] = v; __syncthreads();
  for (int off = 1; off < 128; off <<= 1){
    int u = (tid >= off) ? lds[tid - off] : 0;
    __syncthreads();
    lds[tid] += u;
    __syncthreads();
  }
  if (tid < NT) toff[tid] = lds[tid] - v;
  if (tid == NT - 1) *rpN = lds[tid];
}

__global__ __launch_bounds__(256) void k_scan_c(const int* __restrict__ hist,
                                                const int* __restrict__ toff,
                                                int* __restrict__ rp,
                                                float* __restrict__ dinv){
  __shared__ int lds[256];
  const int tid = threadIdx.x;
  const int base = blockIdx.x * TILE + tid*4;
  int h[4]; int s = 0;
  #pragma unroll
  for (int j = 0; j < 4; ++j){ int idx = base + j; h[j] = (idx < NN) ? hist[idx] : 0; s += h[j]; }
  lds[tid] = s; __syncthreads();
  for (int off = 1; off < 256; off <<= 1){
    int u = (tid >= off) ? lds[tid - off] : 0;
    __syncthreads();
    lds[tid] += u;
    __syncthreads();
  }
  int run = toff[blockIdx.x] + lds[tid] - s;
  #pragma unroll
  for (int j = 0; j < 4; ++j){
    int idx = base + j;
    if (idx < NN){
      rp[idx] = run; run += h[j];
      dinv[idx] = rsqrtf((float)h[j] + 1.f);
    }
  }
}

// ---- chunk-private binning: each block bins its 6250 edges by dst>>6 into its own region ----
// edge packed as (src<<6) | (dst&63)
__global__ __launch_bounds__(256) void k_binA(const int* __restrict__ src, const int* __restrict__ dst,
                                              uint* __restrict__ priv, int* __restrict__ seg){
  __shared__ int hist[NB];
  __shared__ int cur[NB];
  __shared__ int scanbuf[256];
  const int c = blockIdx.x, tid = threadIdx.x;
  const size_t e0 = (size_t)c * CHUNK;
  for (int i = tid; i < NB; i += 256) hist[i] = 0;
  __syncthreads();
  for (int i = tid; i < CHUNK; i += 256) atomicAdd(&hist[dst[e0+i] >> 6], 1);
  __syncthreads();
  int loc[7]; int s = 0;
  const int base = tid * 7;
  #pragma unroll
  for (int j = 0; j < 7; ++j){ int idx = base+j; int v = (idx < NB) ? hist[idx] : 0; loc[j] = s; s += v; }
  scanbuf[tid] = s;
  __syncthreads();
  for (int off = 1; off < 256; off <<= 1){
    int u = (tid >= off) ? scanbuf[tid-off] : 0;
    __syncthreads();
    scanbuf[tid] += u;
    __syncthreads();
  }
  const int run = scanbuf[tid] - s;
  #pragma unroll
  for (int j = 0; j < 7; ++j){
    int idx = base+j;
    if (idx < NB){ int st = run + loc[j]; seg[c*(NB+1)+idx] = st; cur[idx] = st; }
  }
  if (tid == 0) seg[c*(NB+1)+NB] = CHUNK;
  __syncthreads();
  for (int i = tid; i < CHUNK; i += 256){
    const uint ss = (uint)src[e0+i], dd = (uint)dst[e0+i];
    const int p = atomicAdd(&cur[dd >> 6], 1);
    priv[(size_t)c*CHUNK + p] = (ss << 6) | (dd & 63u);
  }
}

// per bucket: scatter chunk-private edges into dst-node-sorted col via rp cursors
__global__ __launch_bounds__(256) void k_gathE2(const uint* __restrict__ priv, const int* __restrict__ seg,
                                                const int* __restrict__ rp, int* __restrict__ col){
  __shared__ int cur[64];
  const int b = blockIdx.x, tid = threadIdx.x;
  const int n0 = b * 64;
  if (tid < 64){
    const int idx = n0 + tid;
    cur[tid] = rp[(idx < NN) ? idx : NN];
  }
  __syncthreads();
  const int c = tid;
  const int s0 = seg[c*(NB+1) + b], s1 = seg[c*(NB+1) + b + 1];
  const size_t pbase = (size_t)c*CHUNK;
  for (int i = s0; i < s1; ++i){
    const uint e = priv[pbase + i];
    const int p = atomicAdd(&cur[e & 63u], 1);
    col[p] = (int)(e >> 6);
  }
}

// weights -> bf16 in per-lane MFMA fragment layout:
// frag id = q*16 + nr*2 + ks ; wimg[frag][lane*8+j] = W[col][k]
//   col = nr*16+(lane&15), k = q*64+ks*32+(lane>>4)*8+j
__global__ __launch_bounds__(256) void k_wprep(const float* __restrict__ sW, const float* __restrict__ bW,
                                               ushort* __restrict__ wimg){
  int idx = blockIdx.x*256 + threadIdx.x;
  if (idx >= NL*WSTRIDE) return;
  const int j    = idx & 7;
  const int lane = (idx >> 3) & 63;
  const int ks   = (idx >> 9) & 1;
  const int nr   = (idx >> 10) & 7;
  const int qq   = (idx >> 13) % NKS;
  const int l    = idx / (NKS << 13);
  const int colc = nr*16 + (lane & 15);
  const int kg   = qq*64 + ks*32 + (lane >> 4)*8 + j;
  const float v  = (kg < KSPL) ? sW[((size_t)l*FEAT + colc)*KSPL + kg]
                               : bW[((size_t)l*FEAT + colc)*FEAT + (kg - KSPL)];
  wimg[idx] = f2bf(v);
}

// ---------------- FKAN transform: LN + in-register RBF + MFMA, row-split waves ----------------
template <typename TIn>
__global__ __launch_bounds__(256, 4) void k_fkan(
    const TIn* __restrict__ xin,            // [NN][128] fp32 or bf16(ushort)
    const ushort* __restrict__ wimg,        // this layer's fragment image (L2-resident)
    const float* __restrict__ ln_s, const float* __restrict__ ln_b,
    const float* __restrict__ sb, const float* __restrict__ bb,
    const float* __restrict__ dinv,
    ushort* __restrict__ hprime)
{
  __shared__ char zb[64*256];        // z bf16 [64][128], xor-swizzled rows
  __shared__ char zs[64*256];        // silu(x) bf16 [64][128], same swizzle
  __shared__ float lnS[128], lnB[128], sbias[128];

  const int tid  = threadIdx.x;
  const int lane = tid & 63, wv = tid >> 6;
  const int node0 = blockIdx.x * BM;

  if (tid < 128){ lnS[tid] = ln_s[tid]; lnB[tid] = ln_b[tid]; sbias[tid] = sb[tid] + bb[tid]; }

  // ---- layernorm phase: 4 threads per node ----
  const int lm = tid >> 2, part = tid & 3;
  const int node = node0 + lm;
  float xv[32];
  if (node < NN){
    if constexpr (sizeof(TIn) == 4){
      const float4* xr = (const float4*)((const float*)xin + (size_t)node*FEAT + part*32);
      #pragma unroll
      for (int j = 0; j < 8; ++j){ float4 v = xr[j]; xv[4*j]=v.x; xv[4*j+1]=v.y; xv[4*j+2]=v.z; xv[4*j+3]=v.w; }
    } else {
      const uint4* xr = (const uint4*)((const ushort*)xin + (size_t)node*FEAT + part*32);
      #pragma unroll
      for (int j = 0; j < 4; ++j){
        uint4 v = xr[j];
        uint w0=v.x, w1=v.y, w2=v.z, w3=v.w;
        xv[8*j+0]=bf2f((ushort)(w0&0xffff)); xv[8*j+1]=bf2f((ushort)(w0>>16));
        xv[8*j+2]=bf2f((ushort)(w1&0xffff)); xv[8*j+3]=bf2f((ushort)(w1>>16));
        xv[8*j+4]=bf2f((ushort)(w2&0xffff)); xv[8*j+5]=bf2f((ushort)(w2>>16));
        xv[8*j+6]=bf2f((ushort)(w3&0xffff)); xv[8*j+7]=bf2f((ushort)(w3>>16));
      }
    }
  } else {
    #pragma unroll
    for (int j = 0; j < 32; ++j) xv[j] = 0.f;
  }
  float s1 = 0.f, s2 = 0.f;
  #pragma unroll
  for (int j = 0; j < 32; ++j){ s1 += xv[j]; s2 += xv[j]*xv[j]; }
  s1 += __shfl_xor(s1, 1); s2 += __shfl_xor(s2, 1);
  s1 += __shfl_xor(s1, 2); s2 += __shfl_xor(s2, 2);
  const float mean = s1 * (1.f/128.f);
  const float var  = s2 * (1.f/128.f) - mean*mean;
  const float rs   = rsqrtf(var + 1e-5f);
  __syncthreads();                       // lnS/lnB staged
  {
    const uint swl = ((uint)(lm & 7)) << 4;
    #pragma unroll
    for (int j = 0; j < 32; j += 2){
      const int f = part*32 + j;
      float z0 = (xv[j]   - mean)*rs*lnS[f]   + lnB[f];
      float z1 = (xv[j+1] - mean)*rs*lnS[f+1] + lnB[f+1];
      *(uint*)(zb + lm*256 + (((uint)(f*2)) ^ swl)) = (uint)f2bf(z0) | ((uint)f2bf(z1) << 16);
      float u0 = fsilu(xv[j]), u1 = fsilu(xv[j+1]);
      *(uint*)(zs + lm*256 + (((uint)(f*2)) ^ swl)) = (uint)f2bf(u0) | ((uint)f2bf(u1) << 16);
    }
  }
  __syncthreads();                       // zb, zs ready -- last barrier

  // ---- barrier-free MFMA K-loop; wave owns rows wv*16..wv*16+15, all 128 cols ----
  const int l15 = lane & 15, l4h = lane >> 4;
  const int row = (wv << 4) + l15;
  const uint swz = ((uint)(row & 7)) << 4;
  const char* zrow = zb + row*256;
  const char* srow = zs + row*256;

  floatx4 acc[8];
  #pragma unroll
  for (int nr = 0; nr < 8; ++nr){ floatx4 z4 = {0.f,0.f,0.f,0.f}; acc[nr] = z4; }

  const short8* w8 = (const short8*)wimg;

  #pragma unroll
  for (int q = 0; q < NKS; ++q){
    #pragma unroll
    for (int ks = 0; ks < 2; ++ks){
      short8 bfr[8];
      #pragma unroll
      for (int nr = 0; nr < 8; ++nr)
        bfr[nr] = w8[(size_t)(q*16 + nr*2 + ks)*64 + lane];

      short8 af;
      if (q < 8){
        const int f0 = q*16 + ks*8 + l4h*2;
        const uint zz = *(const uint*)(zrow + (((uint)(f0*2)) ^ swz));
        const float z0 = bf2f((ushort)(zz & 0xffff)), z1 = bf2f((ushort)(zz >> 16));
        float a0[4], a1[4];
        #pragma unroll
        for (int g = 0; g < 4; ++g){
          const float gc = -2.f + (4.f/3.f)*(float)g;
          const float t0 = (z0 - gc)*0.75f;
          const float t1 = (z1 - gc)*0.75f;
          a0[g] = __expf(-t0*t0);
          a1[g] = __expf(-t1*t1);
        }
        // truncating bf16x2 packs via v_perm (basis in (0,1], 4x absmax headroom)
        uintx4 pw;
        pw.x = __builtin_amdgcn_perm(bu(a0[1]), bu(a0[0]), 0x07060302u);
        pw.y = __builtin_amdgcn_perm(bu(a0[3]), bu(a0[2]), 0x07060302u);
        pw.z = __builtin_amdgcn_perm(bu(a1[1]), bu(a1[0]), 0x07060302u);
        pw.w = __builtin_amdgcn_perm(bu(a1[3]), bu(a1[2]), 0x07060302u);
        af = __builtin_bit_cast(short8, pw);
      } else {
        const int f0 = (q - 8)*64 + ks*32 + l4h*8;
        af = *(const short8*)(srow + (((uint)(f0*2)) ^ swz));
      }
      #pragma unroll
      for (int nr = 0; nr < 8; ++nr)
        acc[nr] = __builtin_amdgcn_mfma_f32_16x16x32_bf16(af, bfr[nr], acc[nr], 0, 0, 0);
    }
  }

  // ---- epilogue: h' = dinv * (acc + bias), bf16 store ----
  const int rbase = node0 + (wv << 4) + l4h*4;
  float dvv[4];
  #pragma unroll
  for (int j = 0; j < 4; ++j) dvv[j] = (rbase + j < NN) ? dinv[rbase + j] : 0.f;
  #pragma unroll
  for (int nr = 0; nr < 8; ++nr){
    const int cf = nr*16 + l15;
    const float sv = sbias[cf];
    #pragma unroll
    for (int j = 0; j < 4; ++j){
      const int r = rbase + j;
      if (r < NN) hprime[(size_t)r*FEAT + cf] = f2bf(dvv[j]*(acc[nr][j] + sv));
    }
  }
}

// ---------------- CSR aggregation + silu + bias (one wave per dst node, register accum) ----------------
__global__ __launch_bounds__(256) void k_aggD(
    const ushort* __restrict__ hprime, const int* __restrict__ rp,
    const int* __restrict__ col, const float* __restrict__ dinv,
    const float* __restrict__ gb, ushort* __restrict__ xout)
{
  const int wv = threadIdx.x >> 6, lane = threadIdx.x & 63;
  const int d = blockIdx.x*4 + wv;
  if (d >= NN) return;
  const uint* h2 = (const uint*)hprime;
  const uint v = h2[(size_t)d*64 + lane];
  float a0 = bf2f((ushort)(v & 0xffff)), a1 = bf2f((ushort)(v >> 16));
  const int j0 = rp[d], j1 = rp[d+1];
  int j = j0;
  for (; j + 7 < j1; j += 8){
    uint w[8];
    #pragma unroll
    for (int u = 0; u < 8; ++u) w[u] = h2[(size_t)col[j+u]*64 + lane];
    #pragma unroll
    for (int u = 0; u < 8; ++u){
      a0 += bf2f((ushort)(w[u] & 0xffff));
      a1 += bf2f((ushort)(w[u] >> 16));
    }
  }
  for (; j + 3 < j1; j += 4){
    uint w[4];
    #pragma unroll
    for (int u = 0; u < 4; ++u) w[u] = h2[(size_t)col[j+u]*64 + lane];
    #pragma unroll
    for (int u = 0; u < 4; ++u){
      a0 += bf2f((ushort)(w[u] & 0xffff));
      a1 += bf2f((ushort)(w[u] >> 16));
    }
  }
  for (; j < j1; ++j){
    const uint w = h2[(size_t)col[j]*64 + lane];
    a0 += bf2f((ushort)(w & 0xffff)); a1 += bf2f((ushort)(w >> 16));
  }
  const float dv = dinv[d];
  const float2 b2 = *(const float2*)(gb + 2*lane);
  a0 = fsilu(dv*a0 + b2.x);
  a1 = fsilu(dv*a1 + b2.y);
  ((uint*)xout)[(size_t)d*64 + lane] = (uint)f2bf(a0) | ((uint)f2bf(a1) << 16);
}

// ---------------- pooling (sorted batch) ----------------
__global__ __launch_bounds__(128) void k_pool(const ushort* __restrict__ x,
                                              const int* __restrict__ batch,
                                              float* __restrict__ pooled,
                                              float* __restrict__ cnt, int n){
  const int f = threadIdx.x;
  const int start = blockIdx.x * 64;
  const int end   = min(start + 64, n);
  if (start >= end) return;
  int cur = batch[start];
  float acc = 0.f, c = 0.f;
  for (int i = start; i < end; ++i){
    const int b = batch[i];
    if (b != cur){
      atomicAdd(&pooled[(size_t)cur*FEAT + f], acc);
      if (f == 0) atomicAdd(&cnt[cur], c);
      cur = b; acc = 0.f; c = 0.f;
    }
    acc += bf2f(x[(size_t)i*FEAT + f]);
    c += 1.f;
  }
  atomicAdd(&pooled[(size_t)cur*FEAT + f], acc);
  if (f == 0) atomicAdd(&cnt[cur], c);
}

__global__ __launch_bounds__(128) void k_pool_div(float* __restrict__ pooled,
                                                  const float* __restrict__ cnt){
  const int g = blockIdx.x, f = threadIdx.x;
  pooled[(size_t)g*FEAT + f] /= fmaxf(cnt[g], 1.f);
}

// ---------------- readout FastKAN (128 -> 10) + log_softmax ----------------
__global__ __launch_bounds__(128) void k_readout(const float* __restrict__ pooled,
    const float* __restrict__ ln_s, const float* __restrict__ ln_b,
    const float* __restrict__ sW, const float* __restrict__ sb,
    const float* __restrict__ bW, const float* __restrict__ bb,
    float* __restrict__ out){
  __shared__ float cb[KSPL + FEAT];
  __shared__ float wred[2][2];
  __shared__ float outv[NCLS];
  const int tid = threadIdx.x, lane = tid & 63, wave = tid >> 6;
  const int g = blockIdx.x;

  const float xvv = pooled[(size_t)g*FEAT + tid];
  float s1 = xvv, s2 = xvv*xvv;
  #pragma unroll
  for (int off = 32; off; off >>= 1){ s1 += __shfl_down(s1, off); s2 += __shfl_down(s2, off); }
  if (lane == 0){ wred[wave][0] = s1; wred[wave][1] = s2; }
  __syncthreads();
  const float m   = (wred[0][0] + wred[1][0]) * (1.f/FEAT);
  const float var = (wred[0][1] + wred[1][1]) * (1.f/FEAT) - m*m;
  const float rs  = rsqrtf(var + 1e-5f);
  const float z   = (xvv - m) * rs * ln_s[tid] + ln_b[tid];
  #pragma unroll
  for (int gg = 0; gg < GQ; ++gg){
    const float t = (z - (-2.f + (4.f/3.f)*(float)gg)) * 0.75f;
    cb[tid*GQ + gg] = __expf(-t*t);
  }
  cb[KSPL + tid] = fsilu(xvv);
  __syncthreads();

  if (tid < NCLS){
    const float* wr = sW + (size_t)tid*KSPL;
    const float* br = bW + (size_t)tid*FEAT;
    float acc = sb[tid] + bb[tid];
    for (int k = 0; k < KSPL; ++k) acc += cb[k] * wr[k];
    for (int k = 0; k < FEAT; ++k) acc += cb[KSPL + k] * br[k];
    outv[tid] = acc;
  }
  __syncthreads();
  if (tid == 0){
    float mx = -1e30f;
    for (int o = 0; o < NCLS; ++o) mx = fmaxf(mx, outv[o]);
    float se = 0.f;
    for (int o = 0; o < NCLS; ++o) se += __expf(outv[o] - mx);
    const float lse = mx + logf(se);
    for (int o = 0; o < NCLS; ++o) out[(size_t)g*NCLS + o] = outv[o] - lse;
  }
}

extern "C" void kernel_launch(void* const* d_in, const int* in_sizes, int n_in,
                              void* d_out, int out_size, void* d_ws, size_t ws_size,
                              hipStream_t stream) {
  const float* x     = (const float*)d_in[0];
  const int*   edge  = (const int*)d_in[1];
  const int*   batch = (const int*)d_in[2];
  const float* ln_s  = (const float*)d_in[3];
  const float* ln_b  = (const float*)d_in[4];
  const float* sW    = (const float*)d_in[5];
  const float* sb    = (const float*)d_in[6];
  const float* bW    = (const float*)d_in[7];
  const float* bb    = (const float*)d_in[8];
  const float* gcn_b = (const float*)d_in[9];
  const float* ro_ln_s = (const float*)d_in[10];
  const float* ro_ln_b = (const float*)d_in[11];
  const float* ro_sW   = (const float*)d_in[12];
  const float* ro_sb   = (const float*)d_in[13];
  const float* ro_bW   = (const float*)d_in[14];
  const float* ro_bb   = (const float*)d_in[15];
  float* out = (float*)d_out;

  const int* src = edge;
  const int* dst = edge + NE;

  char* W = (char*)d_ws;
  size_t off = 0;
  auto alloc = [&](size_t bytes){ size_t r = off; off += (bytes + 1023) & ~((size_t)1023); return r; };
  float*  dinv   = (float*) (W + alloc((size_t)NN*4));
  ushort* wimg   = (ushort*)(W + alloc((size_t)NL*WSTRIDE*2));
  int*    hist   = (int*)   (W + alloc((size_t)NN*4));
  int*    rp     = (int*)   (W + alloc((size_t)(NN+1)*4));
  int*    tsum   = (int*)   (W + alloc((size_t)NT*4));
  int*    toff   = (int*)   (W + alloc((size_t)NT*4));
  uint*   priv   = (uint*)  (W + alloc((size_t)NE*4));
  int*    seg    = (int*)   (W + alloc((size_t)NCHUNK*(NB+1)*4));
  int*    col    = (int*)   (W + alloc((size_t)NE*4));
  ushort* hprime = (ushort*)(W + alloc((size_t)NN*FEAT*2));
  ushort* xcur   = (ushort*)(W + alloc((size_t)NN*FEAT*2));
  float*  pooled = (float*) (W + alloc((size_t)(NGR*FEAT + NGR)*4));
  float*  cnt    = pooled + NGR*FEAT;

  // degree norm + CSR build (layer-invariant)
  k_zero_i<<<(NN+255)/256, 256, 0, stream>>>(hist, NN);
  k_zero_f<<<(NGR*FEAT+NGR+255)/256, 256, 0, stream>>>(pooled, NGR*FEAT + NGR);
  k_hist<<<(NE+255)/256, 256, 0, stream>>>(dst, hist, NE);
  k_scan_a<<<NT, 256, 0, stream>>>(hist, tsum);
  k_scan_b<<<1, 128, 0, stream>>>(tsum, toff, rp + NN);
  k_scan_c<<<NT, 256, 0, stream>>>(hist, toff, rp, dinv);
  k_binA<<<NCHUNK, 256, 0, stream>>>(src, dst, priv, seg);
  k_gathE2<<<NB, 256, 0, stream>>>(priv, seg, rp, col);
  k_wprep<<<(NL*WSTRIDE + 255)/256, 256, 0, stream>>>(sW, bW, wimg);

  const int fkan_grid = (NN + BM - 1) / BM;
  for (int l = 0; l < NL; ++l){
    const ushort* wl = wimg + (size_t)l*WSTRIDE;
    if (l == 0)
      k_fkan<float><<<fkan_grid, 256, 0, stream>>>(x, wl,
          ln_s + l*FEAT, ln_b + l*FEAT, sb + l*FEAT, bb + l*FEAT, dinv, hprime);
    else
      k_fkan<ushort><<<fkan_grid, 256, 0, stream>>>(xcur, wl,
          ln_s + l*FEAT, ln_b + l*FEAT, sb + l*FEAT, bb + l*FEAT, dinv, hprime);
    k_aggD<<<(NN+3)/4, 256, 0, stream>>>(hprime, rp, col, dinv, gcn_b + l*FEAT, xcur);
  }

  k_pool<<<(NN+63)/64, 128, 0, stream>>>(xcur, batch, pooled, cnt, NN);
  k_pool_div<<<NGR, 128, 0, stream>>>(pooled, cnt);
  k_readout<<<NGR, 128, 0, stream>>>(pooled, ro_ln_s, ro_ln_b,
                                     ro_sW, ro_sb, ro_bW, ro_bb, out);
}